// Round 1
// baseline (1192.966 us; speedup 1.0000x reference)
//
#include <hip/hip_runtime.h>
#include <math.h>

#define DIMX 384
#define SEQL 2048
#define NBATCH 2
#define DINNER 768
#define NSTATE 16
#define DTRANK 24
#define NTOK (NBATCH*SEQL)

__device__ __forceinline__ float silu_f(float x) {
  return x / (1.f + __expf(-x));
}

// ---------------- GEMM1: H[m][j] = sum_k X[m][k]*W[j][k] + bias[j] ----------------
__global__ __launch_bounds__(256) void k_lin(const float* __restrict__ X,
    const float* __restrict__ W, const float* __restrict__ bias,
    float* __restrict__ H) {
  __shared__ __align__(16) float As[16][68];
  __shared__ __align__(16) float Bs[16][68];
  const int m0 = blockIdx.x * 64;
  const int j0 = blockIdx.y * 64;
  const int tid = threadIdx.x;
  const int tj = tid & 15, tm = tid >> 4;
  const int lrow = tid >> 2, lkf = (tid & 3) * 4;
  float acc[4][4] = {};
  for (int k0 = 0; k0 < DIMX; k0 += 16) {
    float4 va = *(const float4*)&X[(size_t)(m0 + lrow) * DIMX + k0 + lkf];
    float4 vb = *(const float4*)&W[(size_t)(j0 + lrow) * DIMX + k0 + lkf];
    As[lkf+0][lrow] = va.x; As[lkf+1][lrow] = va.y; As[lkf+2][lrow] = va.z; As[lkf+3][lrow] = va.w;
    Bs[lkf+0][lrow] = vb.x; Bs[lkf+1][lrow] = vb.y; Bs[lkf+2][lrow] = vb.z; Bs[lkf+3][lrow] = vb.w;
    __syncthreads();
#pragma unroll
    for (int kk = 0; kk < 16; ++kk) {
      float4 a = *(const float4*)&As[kk][tm*4];
      float4 b = *(const float4*)&Bs[kk][tj*4];
      float av[4] = {a.x,a.y,a.z,a.w}, bv[4] = {b.x,b.y,b.z,b.w};
#pragma unroll
      for (int i=0;i<4;++i)
#pragma unroll
        for (int j=0;j<4;++j) acc[i][j] = fmaf(av[i], bv[j], acc[i][j]);
    }
    __syncthreads();
  }
  float4 bb = *(const float4*)&bias[j0 + tj*4];
  float bv4[4] = {bb.x,bb.y,bb.z,bb.w};
#pragma unroll
  for (int i=0;i<4;++i) {
    float4 v = { acc[i][0]+bv4[0], acc[i][1]+bv4[1], acc[i][2]+bv4[2], acc[i][3]+bv4[3] };
    *(float4*)&H[(size_t)(m0 + tm*4 + i) * DIMX + j0 + tj*4] = v;
  }
}

// ---------------- LayerNorm + ReLU (in place on H) ----------------
__global__ __launch_bounds__(128) void k_ln(float* __restrict__ H,
    const float* __restrict__ g, const float* __restrict__ bt) {
  const int tok = blockIdx.x;
  float* row = H + (size_t)tok * DIMX;
  const int tid = threadIdx.x;
  float v[3]; float s = 0.f, ss = 0.f;
#pragma unroll
  for (int i = 0; i < 3; ++i) { v[i] = row[tid + i*128]; s += v[i]; ss += v[i]*v[i]; }
  for (int o = 32; o; o >>= 1) { s += __shfl_down(s, o); ss += __shfl_down(ss, o); }
  __shared__ float red[4];
  if ((tid & 63) == 0) { red[(tid>>6)*2] = s; red[(tid>>6)*2+1] = ss; }
  __syncthreads();
  float S = red[0] + red[2], SS = red[1] + red[3];
  float mu = S / DIMX;
  float var = SS / DIMX - mu * mu;
  float inv = rsqrtf(var + 1e-5f);
#pragma unroll
  for (int i = 0; i < 3; ++i) {
    int j = tid + i*128;
    float t = (v[i] - mu) * inv * g[j] + bt[j];
    row[j] = t > 0.f ? t : 0.f;
  }
}

// ---------------- GEMM2: XZ[b][c][l] = sum_k H[b][l][k]*W2[c][k] ----------------
__global__ __launch_bounds__(256) void k_inproj(const float* __restrict__ H,
    const float* __restrict__ W2, float* __restrict__ XZ) {
  __shared__ __align__(16) float Cs[16][68];
  __shared__ __align__(16) float Ls[16][68];
  const int bid = blockIdx.x;
  const int b = bid >> 5;
  const int l0 = (bid & 31) * 64;
  const int c0 = blockIdx.y * 64;
  const int tid = threadIdx.x;
  const int tl = tid & 15, tc = tid >> 4;
  const int lrow = tid >> 2, lkf = (tid & 3) * 4;
  float acc[4][4] = {};
  for (int k0 = 0; k0 < DIMX; k0 += 16) {
    float4 vc = *(const float4*)&W2[(size_t)(c0 + lrow) * DIMX + k0 + lkf];
    float4 vl = *(const float4*)&H[(size_t)(b*SEQL + l0 + lrow) * DIMX + k0 + lkf];
    Cs[lkf+0][lrow] = vc.x; Cs[lkf+1][lrow] = vc.y; Cs[lkf+2][lrow] = vc.z; Cs[lkf+3][lrow] = vc.w;
    Ls[lkf+0][lrow] = vl.x; Ls[lkf+1][lrow] = vl.y; Ls[lkf+2][lrow] = vl.z; Ls[lkf+3][lrow] = vl.w;
    __syncthreads();
#pragma unroll
    for (int kk = 0; kk < 16; ++kk) {
      float4 a = *(const float4*)&Cs[kk][tc*4];
      float4 b4 = *(const float4*)&Ls[kk][tl*4];
      float av[4] = {a.x,a.y,a.z,a.w}, bv[4] = {b4.x,b4.y,b4.z,b4.w};
#pragma unroll
      for (int i=0;i<4;++i)
#pragma unroll
        for (int j=0;j<4;++j) acc[i][j] = fmaf(av[i], bv[j], acc[i][j]);
    }
    __syncthreads();
  }
#pragma unroll
  for (int i=0;i<4;++i) {
    float4 v = { acc[i][0], acc[i][1], acc[i][2], acc[i][3] };
    *(float4*)&XZ[(size_t)(b*(2*DINNER) + c0 + tc*4 + i) * SEQL + l0 + tl*4] = v;
  }
}

// ---------------- causal depthwise conv + silu (both directions) ----------------
__global__ __launch_bounds__(256) void k_conv(const float* __restrict__ XZ,
    const float* __restrict__ cw, const float* __restrict__ cb,
    float* __restrict__ XC) {
  const int idx = blockIdx.x * 256 + threadIdx.x;  // over 2*NB*DI*L
  const int t = idx & (SEQL - 1);
  const int c = idx >> 11;
  const int d = c % DINNER;
  const int bb = c / DINNER;
  const int b = bb & (NBATCH - 1);
  const int dir = bb >> 1;
  const float* row = XZ + (size_t)(b*(2*DINNER) + d) * SEQL;
  float s = cb[d];
  const float w0 = cw[d*4+0], w1 = cw[d*4+1], w2 = cw[d*4+2], w3 = cw[d*4+3];
  if (dir == 0) {
    if (t >= 3) s += w0 * row[t-3];
    if (t >= 2) s += w1 * row[t-2];
    if (t >= 1) s += w2 * row[t-1];
    s += w3 * row[t];
  } else {
    // flipped frame: xcbar[t] = sum_j w[j]*xz[L-1-t+3-j]
    int base = SEQL - 1 - t;
    if (base + 3 < SEQL) s += w0 * row[base+3];
    if (base + 2 < SEQL) s += w1 * row[base+2];
    if (base + 1 < SEQL) s += w2 * row[base+1];
    s += w3 * row[base];
  }
  XC[idx] = silu_f(s);
}

// ---------------- x_proj: dt rows + repacked B/C ----------------
__global__ __launch_bounds__(256) void k_xproj(const float* __restrict__ XC,
    const float* __restrict__ XPW, float* __restrict__ DTR, float* __restrict__ BC) {
  __shared__ float As[64][33];
  __shared__ float Ws[64][57];
  const int bid = blockIdx.x;
  const int l0 = (bid % (SEQL/32)) * 32;
  const int rest = bid / (SEQL/32);
  const int b = rest & (NBATCH - 1);
  const int dir = rest >> 1;
  const int tid = threadIdx.x;
  const int ll = tid & 31, g = tid >> 5;  // 8 groups x 7 outputs
  const float* xc = XC + (size_t)((dir*NBATCH + b) * DINNER) * SEQL;
  float acc[7] = {};
  for (int k0 = 0; k0 < DINNER; k0 += 64) {
#pragma unroll
    for (int i = 0; i < 8; ++i) {
      int e = tid + i*256;
      int kk = e >> 5, cc = e & 31;
      As[kk][cc] = xc[(size_t)(k0 + kk) * SEQL + l0 + cc];
    }
#pragma unroll
    for (int i = 0; i < 14; ++i) {
      int e = tid + i*256;
      if (e < 64*56) { int kk = e / 56, n = e % 56; Ws[kk][n] = XPW[(size_t)n * DINNER + k0 + kk]; }
    }
    __syncthreads();
#pragma unroll 8
    for (int kk = 0; kk < 64; ++kk) {
      float a = As[kk][ll];
#pragma unroll
      for (int i = 0; i < 7; ++i) acc[i] = fmaf(a, Ws[kk][g*7+i], acc[i]);
    }
    __syncthreads();
  }
  const int t = l0 + ll;
#pragma unroll
  for (int i = 0; i < 7; ++i) {
    int n = g*7 + i;
    if (n < DTRANK)
      DTR[(size_t)((dir*NBATCH + b) * DTRANK + n) * SEQL + t] = acc[i];
    else
      BC[((size_t)(dir*NBATCH + b) * SEQL + t) * 32 + (n - DTRANK)] = acc[i];
  }
}

// ---------------- dt_proj + softplus -> delta ----------------
__global__ __launch_bounds__(256) void k_dtproj(const float* __restrict__ DTR,
    const float* __restrict__ WDT, const float* __restrict__ BDT,
    float* __restrict__ DELTA) {
  __shared__ float S[DTRANK][256];
  const int t0 = blockIdx.x * 256;
  const int d0 = blockIdx.y * 8;
  const int db = blockIdx.z;  // dir*NBATCH + b
  const int tid = threadIdx.x;
  const float* src = DTR + (size_t)(db * DTRANK) * SEQL;
#pragma unroll
  for (int r = 0; r < DTRANK; ++r) S[r][tid] = src[(size_t)r * SEQL + t0 + tid];
  __syncthreads();
#pragma unroll
  for (int i = 0; i < 8; ++i) {
    int d = d0 + i;
    float s = BDT[d];
#pragma unroll
    for (int r = 0; r < DTRANK; ++r) s = fmaf(WDT[d*DTRANK + r], S[r][tid], s);
    // stable softplus
    float sp = fmaxf(s, 0.f) + log1pf(__expf(-fabsf(s)));
    DELTA[(size_t)(db * DINNER + d) * SEQL + t0 + tid] = sp;
  }
}

// ---------------- selective scan (both dirs), gating fused ----------------
__global__ __launch_bounds__(256) void k_scan(const float* __restrict__ DELTA,
    const float* __restrict__ XC, const float* __restrict__ BC,
    const float* __restrict__ XZ, const float* __restrict__ Alog,
    const float* __restrict__ Ablog, const float* __restrict__ Dp,
    float* __restrict__ Y) {
  const int tid = threadIdx.x;
  const int n = tid & 15;
  const int ch = blockIdx.x * 16 + (tid >> 4);  // over 2*NB*DI channels
  const int d = ch % DINNER;
  const int rest = ch / DINNER;
  const int b = rest & (NBATCH - 1);
  const int dir = rest >> 1;
  const float Aval = -__expf((dir ? Ablog : Alog)[d * NSTATE + n]);
  const float Dd = Dp[d];
  const float* dlt_p = DELTA + (size_t)((dir*NBATCH + b) * DINNER + d) * SEQL;
  const float* xc_p  = XC   + (size_t)((dir*NBATCH + b) * DINNER + d) * SEQL;
  const float* bc_p  = BC   + (size_t)((dir*NBATCH + b)) * SEQL * 32;
  const float* z_p   = XZ   + (size_t)(b*(2*DINNER) + DINNER + d) * SEQL;
  float* y_p = Y + (size_t)((dir*NBATCH + b) * DINNER + d) * SEQL;
  float h = 0.f;
#pragma unroll 8
  for (int t = 0; t < SEQL; ++t) {
    float dlt = dlt_p[t];
    float xv  = xc_p[t];
    float bn  = bc_p[t*32 + n];
    float cn  = bc_p[t*32 + 16 + n];
    float dA = __expf(dlt * Aval);
    h = fmaf(dA, h, dlt * xv * bn);
    float py = h * cn;
    py += __shfl_xor(py, 8, 16);
    py += __shfl_xor(py, 4, 16);
    py += __shfl_xor(py, 2, 16);
    py += __shfl_xor(py, 1, 16);
    if (n == 0) {
      int to = dir ? (SEQL - 1 - t) : t;
      float z = z_p[to];
      float yv = py + xv * Dd;
      y_p[to] = yv * silu_f(z);
    }
  }
}

// ---------------- out_proj + residual ----------------
__global__ __launch_bounds__(256) void k_outproj(const float* __restrict__ Y,
    const float* __restrict__ WO, const float* __restrict__ X,
    float* __restrict__ OUT) {
  __shared__ __align__(16) float As[16][68];  // [kk][ll] y-sum
  __shared__ __align__(16) float Bs[16][68];  // [kk][oo] WO
  const int bid = blockIdx.x;
  const int b = bid >> 5;
  const int l0 = (bid & 31) * 64;
  const int o0 = blockIdx.y * 64;
  const int tid = threadIdx.x;
  const int to = tid & 15, tl = tid >> 4;
  const float* y0 = Y + (size_t)(b * DINNER) * SEQL;
  const float* y1 = Y + (size_t)((NBATCH + b) * DINNER) * SEQL;
  float acc[4][4] = {};
  const int akk = tid >> 4, alf = (tid & 15) * 4;
  const int boo = tid >> 2, bkf = (tid & 3) * 4;
  for (int k0 = 0; k0 < DINNER; k0 += 16) {
    float4 a0 = *(const float4*)&y0[(size_t)(k0 + akk) * SEQL + l0 + alf];
    float4 a1 = *(const float4*)&y1[(size_t)(k0 + akk) * SEQL + l0 + alf];
    float4 asum = { a0.x+a1.x, a0.y+a1.y, a0.z+a1.z, a0.w+a1.w };
    *(float4*)&As[akk][alf] = asum;
    float4 w = *(const float4*)&WO[(size_t)(o0 + boo) * DINNER + k0 + bkf];
    Bs[bkf+0][boo] = w.x; Bs[bkf+1][boo] = w.y; Bs[bkf+2][boo] = w.z; Bs[bkf+3][boo] = w.w;
    __syncthreads();
#pragma unroll
    for (int kk = 0; kk < 16; ++kk) {
      float4 a = *(const float4*)&As[kk][tl*4];
      float4 b4 = *(const float4*)&Bs[kk][to*4];
      float av[4] = {a.x,a.y,a.z,a.w}, bv[4] = {b4.x,b4.y,b4.z,b4.w};
#pragma unroll
      for (int i=0;i<4;++i)
#pragma unroll
        for (int j=0;j<4;++j) acc[i][j] = fmaf(av[i], bv[j], acc[i][j]);
    }
    __syncthreads();
  }
#pragma unroll
  for (int i=0;i<4;++i) {
    int row = l0 + tl*4 + i;
    size_t off = (size_t)(b*SEQL + row) * DIMX + o0 + to*4;
    float4 xs = *(const float4*)&X[off];
    float4 v = { acc[i][0]+xs.x, acc[i][1]+xs.y, acc[i][2]+xs.z, acc[i][3]+xs.w };
    *(float4*)&OUT[off] = v;
  }
}

extern "C" void kernel_launch(void* const* d_in, const int* in_sizes, int n_in,
                              void* d_out, int out_size, void* d_ws, size_t ws_size,
                              hipStream_t stream) {
  (void)in_sizes; (void)n_in; (void)out_size; (void)ws_size;
  const float* x         = (const float*)d_in[0];
  const float* lin_w     = (const float*)d_in[1];
  const float* lin_b     = (const float*)d_in[2];
  const float* ln_g      = (const float*)d_in[3];
  const float* ln_b      = (const float*)d_in[4];
  const float* in_proj_w = (const float*)d_in[5];
  const float* conv_w    = (const float*)d_in[6];
  const float* conv_b    = (const float*)d_in[7];
  const float* x_proj_w  = (const float*)d_in[8];
  const float* dt_proj_w = (const float*)d_in[9];
  const float* dt_proj_b = (const float*)d_in[10];
  const float* A_log     = (const float*)d_in[11];
  const float* A_b_log   = (const float*)d_in[12];
  const float* Dp        = (const float*)d_in[13];
  const float* out_proj_w= (const float*)d_in[14];
  float* out = (float*)d_out;

  float* ws = (float*)d_ws;
  float* h   = ws;  ws += (size_t)NTOK * DIMX;
  float* xz  = ws;  ws += (size_t)NBATCH * 2*DINNER * SEQL;
  float* xc  = ws;  ws += (size_t)2 * NBATCH * DINNER * SEQL;
  float* dlt = ws;  ws += (size_t)2 * NBATCH * DINNER * SEQL;
  float* dtr = ws;  ws += (size_t)2 * NBATCH * DTRANK * SEQL;
  float* bc  = ws;  ws += (size_t)2 * NBATCH * SEQL * 32;
  float* y01 = ws;  ws += (size_t)2 * NBATCH * DINNER * SEQL;

  k_lin<<<dim3(NTOK/64, DIMX/64), 256, 0, stream>>>(x, lin_w, lin_b, h);
  k_ln<<<NTOK, 128, 0, stream>>>(h, ln_g, ln_b);
  k_inproj<<<dim3(NBATCH*SEQL/64, 2*DINNER/64), 256, 0, stream>>>(h, in_proj_w, xz);
  k_conv<<<(2*NBATCH*DINNER*SEQL)/256, 256, 0, stream>>>(xz, conv_w, conv_b, xc);
  k_xproj<<<2*NBATCH*(SEQL/32), 256, 0, stream>>>(xc, x_proj_w, dtr, bc);
  k_dtproj<<<dim3(SEQL/256, DINNER/8, 2*NBATCH), 256, 0, stream>>>(dtr, dt_proj_w, dt_proj_b, dlt);
  k_scan<<<(2*NBATCH*DINNER)/16, 256, 0, stream>>>(dlt, xc, bc, xz, A_log, A_b_log, Dp, y01);
  k_outproj<<<dim3(NBATCH*SEQL/64, DIMX/64), 256, 0, stream>>>(y01, out_proj_w, x, out);
}

// Round 2
// 497.032 us; speedup vs baseline: 2.4002x; 2.4002x over previous
//
#include <hip/hip_runtime.h>
#include <math.h>

#define DIMX 384
#define SEQL 2048
#define NBATCH 2
#define DINNER 768
#define NSTATE 16
#define DTRANK 24
#define NTOK (NBATCH*SEQL)
#define NCHUNK 16
#define CHUNK (SEQL/NCHUNK)   // 128
#define NCH (2*NBATCH*DINNER) // 3072 channels (dir,b,d)

__device__ __forceinline__ float silu_f(float x) {
  return x / (1.f + __expf(-x));
}

// ---------------- GEMM1: H[m][j] = sum_k X[m][k]*W[j][k] + bias[j] ----------------
__global__ __launch_bounds__(256) void k_lin(const float* __restrict__ X,
    const float* __restrict__ W, const float* __restrict__ bias,
    float* __restrict__ H) {
  __shared__ __align__(16) float As[16][68];
  __shared__ __align__(16) float Bs[16][68];
  const int m0 = blockIdx.x * 64;
  const int j0 = blockIdx.y * 64;
  const int tid = threadIdx.x;
  const int tj = tid & 15, tm = tid >> 4;
  const int lrow = tid >> 2, lkf = (tid & 3) * 4;
  float acc[4][4] = {};
  for (int k0 = 0; k0 < DIMX; k0 += 16) {
    float4 va = *(const float4*)&X[(size_t)(m0 + lrow) * DIMX + k0 + lkf];
    float4 vb = *(const float4*)&W[(size_t)(j0 + lrow) * DIMX + k0 + lkf];
    As[lkf+0][lrow] = va.x; As[lkf+1][lrow] = va.y; As[lkf+2][lrow] = va.z; As[lkf+3][lrow] = va.w;
    Bs[lkf+0][lrow] = vb.x; Bs[lkf+1][lrow] = vb.y; Bs[lkf+2][lrow] = vb.z; Bs[lkf+3][lrow] = vb.w;
    __syncthreads();
#pragma unroll
    for (int kk = 0; kk < 16; ++kk) {
      float4 a = *(const float4*)&As[kk][tm*4];
      float4 b = *(const float4*)&Bs[kk][tj*4];
      float av[4] = {a.x,a.y,a.z,a.w}, bv[4] = {b.x,b.y,b.z,b.w};
#pragma unroll
      for (int i=0;i<4;++i)
#pragma unroll
        for (int j=0;j<4;++j) acc[i][j] = fmaf(av[i], bv[j], acc[i][j]);
    }
    __syncthreads();
  }
  float4 bb = *(const float4*)&bias[j0 + tj*4];
  float bv4[4] = {bb.x,bb.y,bb.z,bb.w};
#pragma unroll
  for (int i=0;i<4;++i) {
    float4 v = { acc[i][0]+bv4[0], acc[i][1]+bv4[1], acc[i][2]+bv4[2], acc[i][3]+bv4[3] };
    *(float4*)&H[(size_t)(m0 + tm*4 + i) * DIMX + j0 + tj*4] = v;
  }
}

// ---------------- LayerNorm + ReLU (in place on H) ----------------
__global__ __launch_bounds__(128) void k_ln(float* __restrict__ H,
    const float* __restrict__ g, const float* __restrict__ bt) {
  const int tok = blockIdx.x;
  float* row = H + (size_t)tok * DIMX;
  const int tid = threadIdx.x;
  float v[3]; float s = 0.f, ss = 0.f;
#pragma unroll
  for (int i = 0; i < 3; ++i) { v[i] = row[tid + i*128]; s += v[i]; ss += v[i]*v[i]; }
  for (int o = 32; o; o >>= 1) { s += __shfl_down(s, o); ss += __shfl_down(ss, o); }
  __shared__ float red[4];
  if ((tid & 63) == 0) { red[(tid>>6)*2] = s; red[(tid>>6)*2+1] = ss; }
  __syncthreads();
  float S = red[0] + red[2], SS = red[1] + red[3];
  float mu = S / DIMX;
  float var = SS / DIMX - mu * mu;
  float inv = rsqrtf(var + 1e-5f);
#pragma unroll
  for (int i = 0; i < 3; ++i) {
    int j = tid + i*128;
    float t = (v[i] - mu) * inv * g[j] + bt[j];
    row[j] = t > 0.f ? t : 0.f;
  }
}

// ---------------- GEMM2: XZ[b][c][l] = sum_k H[b][l][k]*W2[c][k] ----------------
__global__ __launch_bounds__(256) void k_inproj(const float* __restrict__ H,
    const float* __restrict__ W2, float* __restrict__ XZ) {
  __shared__ __align__(16) float Cs[16][68];
  __shared__ __align__(16) float Ls[16][68];
  const int bid = blockIdx.x;
  const int b = bid >> 5;
  const int l0 = (bid & 31) * 64;
  const int c0 = blockIdx.y * 64;
  const int tid = threadIdx.x;
  const int tl = tid & 15, tc = tid >> 4;
  const int lrow = tid >> 2, lkf = (tid & 3) * 4;
  float acc[4][4] = {};
  for (int k0 = 0; k0 < DIMX; k0 += 16) {
    float4 vc = *(const float4*)&W2[(size_t)(c0 + lrow) * DIMX + k0 + lkf];
    float4 vl = *(const float4*)&H[(size_t)(b*SEQL + l0 + lrow) * DIMX + k0 + lkf];
    Cs[lkf+0][lrow] = vc.x; Cs[lkf+1][lrow] = vc.y; Cs[lkf+2][lrow] = vc.z; Cs[lkf+3][lrow] = vc.w;
    Ls[lkf+0][lrow] = vl.x; Ls[lkf+1][lrow] = vl.y; Ls[lkf+2][lrow] = vl.z; Ls[lkf+3][lrow] = vl.w;
    __syncthreads();
#pragma unroll
    for (int kk = 0; kk < 16; ++kk) {
      float4 a = *(const float4*)&Cs[kk][tc*4];
      float4 b4 = *(const float4*)&Ls[kk][tl*4];
      float av[4] = {a.x,a.y,a.z,a.w}, bv[4] = {b4.x,b4.y,b4.z,b4.w};
#pragma unroll
      for (int i=0;i<4;++i)
#pragma unroll
        for (int j=0;j<4;++j) acc[i][j] = fmaf(av[i], bv[j], acc[i][j]);
    }
    __syncthreads();
  }
#pragma unroll
  for (int i=0;i<4;++i) {
    float4 v = { acc[i][0], acc[i][1], acc[i][2], acc[i][3] };
    *(float4*)&XZ[(size_t)(b*(2*DINNER) + c0 + tc*4 + i) * SEQL + l0 + tl*4] = v;
  }
}

// ---------------- causal depthwise conv + silu (both directions) ----------------
__global__ __launch_bounds__(256) void k_conv(const float* __restrict__ XZ,
    const float* __restrict__ cw, const float* __restrict__ cb,
    float* __restrict__ XC) {
  const int idx = blockIdx.x * 256 + threadIdx.x;  // over 2*NB*DI*L
  const int t = idx & (SEQL - 1);
  const int c = idx >> 11;
  const int d = c % DINNER;
  const int bb = c / DINNER;
  const int b = bb & (NBATCH - 1);
  const int dir = bb >> 1;
  const float* row = XZ + (size_t)(b*(2*DINNER) + d) * SEQL;
  float s = cb[d];
  const float w0 = cw[d*4+0], w1 = cw[d*4+1], w2 = cw[d*4+2], w3 = cw[d*4+3];
  if (dir == 0) {
    if (t >= 3) s += w0 * row[t-3];
    if (t >= 2) s += w1 * row[t-2];
    if (t >= 1) s += w2 * row[t-1];
    s += w3 * row[t];
  } else {
    int base = SEQL - 1 - t;
    if (base + 3 < SEQL) s += w0 * row[base+3];
    if (base + 2 < SEQL) s += w1 * row[base+2];
    if (base + 1 < SEQL) s += w2 * row[base+1];
    s += w3 * row[base];
  }
  XC[idx] = silu_f(s);
}

// ---------------- x_proj: dt rows + repacked B/C ----------------
__global__ __launch_bounds__(256) void k_xproj(const float* __restrict__ XC,
    const float* __restrict__ XPW, float* __restrict__ DTR, float* __restrict__ BC) {
  __shared__ float As[64][33];
  __shared__ float Ws[64][57];
  const int bid = blockIdx.x;
  const int l0 = (bid % (SEQL/32)) * 32;
  const int rest = bid / (SEQL/32);
  const int b = rest & (NBATCH - 1);
  const int dir = rest >> 1;
  const int tid = threadIdx.x;
  const int ll = tid & 31, g = tid >> 5;  // 8 groups x 7 outputs
  const float* xc = XC + (size_t)((dir*NBATCH + b) * DINNER) * SEQL;
  float acc[7] = {};
  for (int k0 = 0; k0 < DINNER; k0 += 64) {
#pragma unroll
    for (int i = 0; i < 8; ++i) {
      int e = tid + i*256;
      int kk = e >> 5, cc = e & 31;
      As[kk][cc] = xc[(size_t)(k0 + kk) * SEQL + l0 + cc];
    }
#pragma unroll
    for (int i = 0; i < 14; ++i) {
      int e = tid + i*256;
      if (e < 64*56) { int kk = e / 56, n = e % 56; Ws[kk][n] = XPW[(size_t)n * DINNER + k0 + kk]; }
    }
    __syncthreads();
#pragma unroll 8
    for (int kk = 0; kk < 64; ++kk) {
      float a = As[kk][ll];
#pragma unroll
      for (int i = 0; i < 7; ++i) acc[i] = fmaf(a, Ws[kk][g*7+i], acc[i]);
    }
    __syncthreads();
  }
  const int t = l0 + ll;
#pragma unroll
  for (int i = 0; i < 7; ++i) {
    int n = g*7 + i;
    if (n < DTRANK)
      DTR[(size_t)((dir*NBATCH + b) * DTRANK + n) * SEQL + t] = acc[i];
    else
      BC[((size_t)(dir*NBATCH + b) * SEQL + t) * 32 + (n - DTRANK)] = acc[i];
  }
}

// ---------------- dt_proj + softplus -> delta ----------------
__global__ __launch_bounds__(256) void k_dtproj(const float* __restrict__ DTR,
    const float* __restrict__ WDT, const float* __restrict__ BDT,
    float* __restrict__ DELTA) {
  __shared__ float S[DTRANK][256];
  const int t0 = blockIdx.x * 256;
  const int d0 = blockIdx.y * 8;
  const int db = blockIdx.z;  // dir*NBATCH + b
  const int tid = threadIdx.x;
  const float* src = DTR + (size_t)(db * DTRANK) * SEQL;
#pragma unroll
  for (int r = 0; r < DTRANK; ++r) S[r][tid] = src[(size_t)r * SEQL + t0 + tid];
  __syncthreads();
#pragma unroll
  for (int i = 0; i < 8; ++i) {
    int d = d0 + i;
    float s = BDT[d];
#pragma unroll
    for (int r = 0; r < DTRANK; ++r) s = fmaf(WDT[d*DTRANK + r], S[r][tid], s);
    float sp = fmaxf(s, 0.f) + log1pf(__expf(-fabsf(s)));
    DELTA[(size_t)(db * DINNER + d) * SEQL + t0 + tid] = sp;
  }
}

// ---------------- chunked selective scan: pass 1 (local scan, h0=0) ----------------
// group = (channel, chunk); 16 lanes = 16 states. Outputs per (ch,chunk,n):
//   P  = prod over chunk of dA
//   HL = local h_end (with h_start = 0)
__global__ __launch_bounds__(256) void k_scan1(const float* __restrict__ DELTA,
    const float* __restrict__ XC, const float* __restrict__ BC,
    const float* __restrict__ Alog, const float* __restrict__ Ablog,
    float* __restrict__ P, float* __restrict__ HL) {
  const int tid = threadIdx.x;
  const int n = tid & 15;
  const int gid = blockIdx.x * 16 + (tid >> 4);   // 0 .. NCH*NCHUNK-1
  const int c = gid & (NCHUNK - 1);
  const int ch = gid >> 4;                        // log2(NCHUNK)=4
  const int d = ch % DINNER;
  const int rest = ch / DINNER;
  const int b = rest & (NBATCH - 1);
  const int dir = rest >> 1;
  const float Aval = -__expf((dir ? Ablog : Alog)[d * NSTATE + n]);
  const float* dlt_p = DELTA + (size_t)((dir*NBATCH + b) * DINNER + d) * SEQL;
  const float* xc_p  = XC   + (size_t)((dir*NBATCH + b) * DINNER + d) * SEQL;
  const float* bc_p  = BC   + (size_t)(dir*NBATCH + b) * SEQL * 32;
  float h = 0.f, p = 1.f;
  const int t0 = c * CHUNK;
#pragma unroll 4
  for (int t = t0; t < t0 + CHUNK; ++t) {
    float dlt = dlt_p[t];
    float xv  = xc_p[t];
    float bn  = bc_p[t*32 + n];
    float dA = __expf(dlt * Aval);
    h = fmaf(dA, h, dlt * xv * bn);
    p *= dA;
  }
  P [(size_t)gid * 16 + n] = p;
  HL[(size_t)gid * 16 + n] = h;
}

// ---------------- chunked scan: fixup (sequential over 16 chunk summaries) ----------------
// thread = (ch, n); writes h_start per (ch, chunk, n)
__global__ __launch_bounds__(256) void k_scanfix(const float* __restrict__ P,
    const float* __restrict__ HL, float* __restrict__ HS) {
  const int idx = blockIdx.x * 256 + threadIdx.x;  // 0 .. NCH*16-1
  const int ch = idx >> 4;
  const int n = idx & 15;
  float h = 0.f;
#pragma unroll
  for (int c = 0; c < NCHUNK; ++c) {
    size_t off = ((size_t)ch * NCHUNK + c) * 16 + n;
    HS[off] = h;
    h = fmaf(P[off], h, HL[off]);
  }
  (void)ch;
}

// ---------------- chunked scan: pass 2 (recompute with true h_start, emit gated y) ----------------
__global__ __launch_bounds__(256) void k_scan2(const float* __restrict__ DELTA,
    const float* __restrict__ XC, const float* __restrict__ BC,
    const float* __restrict__ XZ, const float* __restrict__ Alog,
    const float* __restrict__ Ablog, const float* __restrict__ Dp,
    const float* __restrict__ HS, float* __restrict__ Y) {
  const int tid = threadIdx.x;
  const int n = tid & 15;
  const int gid = blockIdx.x * 16 + (tid >> 4);
  const int c = gid & (NCHUNK - 1);
  const int ch = gid >> 4;
  const int d = ch % DINNER;
  const int rest = ch / DINNER;
  const int b = rest & (NBATCH - 1);
  const int dir = rest >> 1;
  const float Aval = -__expf((dir ? Ablog : Alog)[d * NSTATE + n]);
  const float Dd = Dp[d];
  const float* dlt_p = DELTA + (size_t)((dir*NBATCH + b) * DINNER + d) * SEQL;
  const float* xc_p  = XC   + (size_t)((dir*NBATCH + b) * DINNER + d) * SEQL;
  const float* bc_p  = BC   + (size_t)(dir*NBATCH + b) * SEQL * 32;
  const float* z_p   = XZ   + (size_t)(b*(2*DINNER) + DINNER + d) * SEQL;
  float* y_p = Y + (size_t)((dir*NBATCH + b) * DINNER + d) * SEQL;
  float h = HS[(size_t)gid * 16 + n];
  const int t0 = c * CHUNK;
#pragma unroll 4
  for (int t = t0; t < t0 + CHUNK; ++t) {
    float dlt = dlt_p[t];
    float xv  = xc_p[t];
    float bn  = bc_p[t*32 + n];
    float cn  = bc_p[t*32 + 16 + n];
    float dA = __expf(dlt * Aval);
    h = fmaf(dA, h, dlt * xv * bn);
    float py = h * cn;
    py += __shfl_xor(py, 8, 16);
    py += __shfl_xor(py, 4, 16);
    py += __shfl_xor(py, 2, 16);
    py += __shfl_xor(py, 1, 16);
    if (n == 0) {
      int to = dir ? (SEQL - 1 - t) : t;
      float z = z_p[to];
      float yv = py + xv * Dd;
      y_p[to] = yv * silu_f(z);
    }
  }
}

// ---------------- out_proj + residual ----------------
__global__ __launch_bounds__(256) void k_outproj(const float* __restrict__ Y,
    const float* __restrict__ WO, const float* __restrict__ X,
    float* __restrict__ OUT) {
  __shared__ __align__(16) float As[16][68];  // [kk][ll] y-sum
  __shared__ __align__(16) float Bs[16][68];  // [kk][oo] WO
  const int bid = blockIdx.x;
  const int b = bid >> 5;
  const int l0 = (bid & 31) * 64;
  const int o0 = blockIdx.y * 64;
  const int tid = threadIdx.x;
  const int to = tid & 15, tl = tid >> 4;
  const float* y0 = Y + (size_t)(b * DINNER) * SEQL;
  const float* y1 = Y + (size_t)((NBATCH + b) * DINNER) * SEQL;
  float acc[4][4] = {};
  const int akk = tid >> 4, alf = (tid & 15) * 4;
  const int boo = tid >> 2, bkf = (tid & 3) * 4;
  for (int k0 = 0; k0 < DINNER; k0 += 16) {
    float4 a0 = *(const float4*)&y0[(size_t)(k0 + akk) * SEQL + l0 + alf];
    float4 a1 = *(const float4*)&y1[(size_t)(k0 + akk) * SEQL + l0 + alf];
    float4 asum = { a0.x+a1.x, a0.y+a1.y, a0.z+a1.z, a0.w+a1.w };
    *(float4*)&As[akk][alf] = asum;
    float4 w = *(const float4*)&WO[(size_t)(o0 + boo) * DINNER + k0 + bkf];
    Bs[bkf+0][boo] = w.x; Bs[bkf+1][boo] = w.y; Bs[bkf+2][boo] = w.z; Bs[bkf+3][boo] = w.w;
    __syncthreads();
#pragma unroll
    for (int kk = 0; kk < 16; ++kk) {
      float4 a = *(const float4*)&As[kk][tl*4];
      float4 b4 = *(const float4*)&Bs[kk][to*4];
      float av[4] = {a.x,a.y,a.z,a.w}, bv[4] = {b4.x,b4.y,b4.z,b4.w};
#pragma unroll
      for (int i=0;i<4;++i)
#pragma unroll
        for (int j=0;j<4;++j) acc[i][j] = fmaf(av[i], bv[j], acc[i][j]);
    }
    __syncthreads();
  }
#pragma unroll
  for (int i=0;i<4;++i) {
    int row = l0 + tl*4 + i;
    size_t off = (size_t)(b*SEQL + row) * DIMX + o0 + to*4;
    float4 xs = *(const float4*)&X[off];
    float4 v = { acc[i][0]+xs.x, acc[i][1]+xs.y, acc[i][2]+xs.z, acc[i][3]+xs.w };
    *(float4*)&OUT[off] = v;
  }
}

extern "C" void kernel_launch(void* const* d_in, const int* in_sizes, int n_in,
                              void* d_out, int out_size, void* d_ws, size_t ws_size,
                              hipStream_t stream) {
  (void)in_sizes; (void)n_in; (void)out_size; (void)ws_size;
  const float* x         = (const float*)d_in[0];
  const float* lin_w     = (const float*)d_in[1];
  const float* lin_b     = (const float*)d_in[2];
  const float* ln_g      = (const float*)d_in[3];
  const float* ln_b      = (const float*)d_in[4];
  const float* in_proj_w = (const float*)d_in[5];
  const float* conv_w    = (const float*)d_in[6];
  const float* conv_b    = (const float*)d_in[7];
  const float* x_proj_w  = (const float*)d_in[8];
  const float* dt_proj_w = (const float*)d_in[9];
  const float* dt_proj_b = (const float*)d_in[10];
  const float* A_log     = (const float*)d_in[11];
  const float* A_b_log   = (const float*)d_in[12];
  const float* Dp        = (const float*)d_in[13];
  const float* out_proj_w= (const float*)d_in[14];
  float* out = (float*)d_out;

  float* ws = (float*)d_ws;
  float* h    = ws;  ws += (size_t)NTOK * DIMX;
  float* xz   = ws;  ws += (size_t)NBATCH * 2*DINNER * SEQL;
  float* xc   = ws;  ws += (size_t)2 * NBATCH * DINNER * SEQL;
  float* dlt  = ws;  ws += (size_t)2 * NBATCH * DINNER * SEQL;
  float* dtr  = ws;  ws += (size_t)2 * NBATCH * DTRANK * SEQL;
  float* bc   = ws;  ws += (size_t)2 * NBATCH * SEQL * 32;
  float* y01  = ws;  ws += (size_t)2 * NBATCH * DINNER * SEQL;
  float* Pbuf = ws;  ws += (size_t)NCH * NCHUNK * 16;
  float* HLb  = ws;  ws += (size_t)NCH * NCHUNK * 16;
  float* HSb  = ws;  ws += (size_t)NCH * NCHUNK * 16;

  k_lin<<<dim3(NTOK/64, DIMX/64), 256, 0, stream>>>(x, lin_w, lin_b, h);
  k_ln<<<NTOK, 128, 0, stream>>>(h, ln_g, ln_b);
  k_inproj<<<dim3(NBATCH*SEQL/64, 2*DINNER/64), 256, 0, stream>>>(h, in_proj_w, xz);
  k_conv<<<(2*NBATCH*DINNER*SEQL)/256, 256, 0, stream>>>(xz, conv_w, conv_b, xc);
  k_xproj<<<2*NBATCH*(SEQL/32), 256, 0, stream>>>(xc, x_proj_w, dtr, bc);
  k_dtproj<<<dim3(SEQL/256, DINNER/8, 2*NBATCH), 256, 0, stream>>>(dtr, dt_proj_w, dt_proj_b, dlt);
  k_scan1<<<NCH*NCHUNK/16, 256, 0, stream>>>(dlt, xc, bc, A_log, A_b_log, Pbuf, HLb);
  k_scanfix<<<NCH*16/256, 256, 0, stream>>>(Pbuf, HLb, HSb);
  k_scan2<<<NCH*NCHUNK/16, 256, 0, stream>>>(dlt, xc, bc, xz, A_log, A_b_log, Dp, HSb, y01);
  k_outproj<<<dim3(NBATCH*SEQL/64, DIMX/64), 256, 0, stream>>>(y01, out_proj_w, x, out);
}

// Round 3
// 392.599 us; speedup vs baseline: 3.0386x; 1.2660x over previous
//
#include <hip/hip_runtime.h>
#include <math.h>

#define DIMX 384
#define SEQL 2048
#define NBATCH 2
#define DINNER 768
#define NSTATE 16
#define DTRANK 24
#define NTOK (NBATCH*SEQL)
#define NCHUNK 32
#define CHUNK (SEQL/NCHUNK)   // 64
#define NCH (2*NBATCH*DINNER) // 3072 channels (dir,b,d)
#define NGRP (NCH*NCHUNK)     // 98304 channel-chunk groups

__device__ __forceinline__ float silu_f(float x) {
  return x / (1.f + __expf(-x));
}

// ---------------- GEMM1: H[m][j] = sum_k X[m][k]*W[j][k] + bias[j] ----------------
__global__ __launch_bounds__(256) void k_lin(const float* __restrict__ X,
    const float* __restrict__ W, const float* __restrict__ bias,
    float* __restrict__ H) {
  __shared__ __align__(16) float As[16][68];
  __shared__ __align__(16) float Bs[16][68];
  const int m0 = blockIdx.x * 64;
  const int j0 = blockIdx.y * 64;
  const int tid = threadIdx.x;
  const int tj = tid & 15, tm = tid >> 4;
  const int lrow = tid >> 2, lkf = (tid & 3) * 4;
  float acc[4][4] = {};
  for (int k0 = 0; k0 < DIMX; k0 += 16) {
    float4 va = *(const float4*)&X[(size_t)(m0 + lrow) * DIMX + k0 + lkf];
    float4 vb = *(const float4*)&W[(size_t)(j0 + lrow) * DIMX + k0 + lkf];
    As[lkf+0][lrow] = va.x; As[lkf+1][lrow] = va.y; As[lkf+2][lrow] = va.z; As[lkf+3][lrow] = va.w;
    Bs[lkf+0][lrow] = vb.x; Bs[lkf+1][lrow] = vb.y; Bs[lkf+2][lrow] = vb.z; Bs[lkf+3][lrow] = vb.w;
    __syncthreads();
#pragma unroll
    for (int kk = 0; kk < 16; ++kk) {
      float4 a = *(const float4*)&As[kk][tm*4];
      float4 b = *(const float4*)&Bs[kk][tj*4];
      float av[4] = {a.x,a.y,a.z,a.w}, bv[4] = {b.x,b.y,b.z,b.w};
#pragma unroll
      for (int i=0;i<4;++i)
#pragma unroll
        for (int j=0;j<4;++j) acc[i][j] = fmaf(av[i], bv[j], acc[i][j]);
    }
    __syncthreads();
  }
  float4 bb = *(const float4*)&bias[j0 + tj*4];
  float bv4[4] = {bb.x,bb.y,bb.z,bb.w};
#pragma unroll
  for (int i=0;i<4;++i) {
    float4 v = { acc[i][0]+bv4[0], acc[i][1]+bv4[1], acc[i][2]+bv4[2], acc[i][3]+bv4[3] };
    *(float4*)&H[(size_t)(m0 + tm*4 + i) * DIMX + j0 + tj*4] = v;
  }
}

// ---------------- LayerNorm + ReLU (in place on H) ----------------
__global__ __launch_bounds__(128) void k_ln(float* __restrict__ H,
    const float* __restrict__ g, const float* __restrict__ bt) {
  const int tok = blockIdx.x;
  float* row = H + (size_t)tok * DIMX;
  const int tid = threadIdx.x;
  float v[3]; float s = 0.f, ss = 0.f;
#pragma unroll
  for (int i = 0; i < 3; ++i) { v[i] = row[tid + i*128]; s += v[i]; ss += v[i]*v[i]; }
  for (int o = 32; o; o >>= 1) { s += __shfl_down(s, o); ss += __shfl_down(ss, o); }
  __shared__ float red[4];
  if ((tid & 63) == 0) { red[(tid>>6)*2] = s; red[(tid>>6)*2+1] = ss; }
  __syncthreads();
  float S = red[0] + red[2], SS = red[1] + red[3];
  float mu = S / DIMX;
  float var = SS / DIMX - mu * mu;
  float inv = rsqrtf(var + 1e-5f);
#pragma unroll
  for (int i = 0; i < 3; ++i) {
    int j = tid + i*128;
    float t = (v[i] - mu) * inv * g[j] + bt[j];
    row[j] = t > 0.f ? t : 0.f;
  }
}

// ---------------- GEMM2: XZ[b][c][l] = sum_k H[b][l][k]*W2[c][k] ----------------
__global__ __launch_bounds__(256) void k_inproj(const float* __restrict__ H,
    const float* __restrict__ W2, float* __restrict__ XZ) {
  __shared__ __align__(16) float Cs[16][68];
  __shared__ __align__(16) float Ls[16][68];
  const int bid = blockIdx.x;
  const int b = bid >> 5;
  const int l0 = (bid & 31) * 64;
  const int c0 = blockIdx.y * 64;
  const int tid = threadIdx.x;
  const int tl = tid & 15, tc = tid >> 4;
  const int lrow = tid >> 2, lkf = (tid & 3) * 4;
  float acc[4][4] = {};
  for (int k0 = 0; k0 < DIMX; k0 += 16) {
    float4 vc = *(const float4*)&W2[(size_t)(c0 + lrow) * DIMX + k0 + lkf];
    float4 vl = *(const float4*)&H[(size_t)(b*SEQL + l0 + lrow) * DIMX + k0 + lkf];
    Cs[lkf+0][lrow] = vc.x; Cs[lkf+1][lrow] = vc.y; Cs[lkf+2][lrow] = vc.z; Cs[lkf+3][lrow] = vc.w;
    Ls[lkf+0][lrow] = vl.x; Ls[lkf+1][lrow] = vl.y; Ls[lkf+2][lrow] = vl.z; Ls[lkf+3][lrow] = vl.w;
    __syncthreads();
#pragma unroll
    for (int kk = 0; kk < 16; ++kk) {
      float4 a = *(const float4*)&Cs[kk][tc*4];
      float4 b4 = *(const float4*)&Ls[kk][tl*4];
      float av[4] = {a.x,a.y,a.z,a.w}, bv[4] = {b4.x,b4.y,b4.z,b4.w};
#pragma unroll
      for (int i=0;i<4;++i)
#pragma unroll
        for (int j=0;j<4;++j) acc[i][j] = fmaf(av[i], bv[j], acc[i][j]);
    }
    __syncthreads();
  }
#pragma unroll
  for (int i=0;i<4;++i) {
    float4 v = { acc[i][0], acc[i][1], acc[i][2], acc[i][3] };
    *(float4*)&XZ[(size_t)(b*(2*DINNER) + c0 + tc*4 + i) * SEQL + l0 + tl*4] = v;
  }
}

// ---------------- causal depthwise conv + silu (both directions) ----------------
__global__ __launch_bounds__(256) void k_conv(const float* __restrict__ XZ,
    const float* __restrict__ cw, const float* __restrict__ cb,
    float* __restrict__ XC) {
  const int idx = blockIdx.x * 256 + threadIdx.x;  // over 2*NB*DI*L
  const int t = idx & (SEQL - 1);
  const int c = idx >> 11;
  const int d = c % DINNER;
  const int bb = c / DINNER;
  const int b = bb & (NBATCH - 1);
  const int dir = bb >> 1;
  const float* row = XZ + (size_t)(b*(2*DINNER) + d) * SEQL;
  float s = cb[d];
  const float w0 = cw[d*4+0], w1 = cw[d*4+1], w2 = cw[d*4+2], w3 = cw[d*4+3];
  if (dir == 0) {
    if (t >= 3) s += w0 * row[t-3];
    if (t >= 2) s += w1 * row[t-2];
    if (t >= 1) s += w2 * row[t-1];
    s += w3 * row[t];
  } else {
    int base = SEQL - 1 - t;
    if (base + 3 < SEQL) s += w0 * row[base+3];
    if (base + 2 < SEQL) s += w1 * row[base+2];
    if (base + 1 < SEQL) s += w2 * row[base+1];
    s += w3 * row[base];
  }
  XC[idx] = silu_f(s);
}

// ---------------- x_proj: dt rows + repacked B/C ----------------
__global__ __launch_bounds__(256) void k_xproj(const float* __restrict__ XC,
    const float* __restrict__ XPW, float* __restrict__ DTR, float* __restrict__ BC) {
  __shared__ float As[64][33];
  __shared__ float Ws[64][57];
  const int bid = blockIdx.x;
  const int l0 = (bid % (SEQL/32)) * 32;
  const int rest = bid / (SEQL/32);
  const int b = rest & (NBATCH - 1);
  const int dir = rest >> 1;
  const int tid = threadIdx.x;
  const int ll = tid & 31, g = tid >> 5;  // 8 groups x 7 outputs
  const float* xc = XC + (size_t)((dir*NBATCH + b) * DINNER) * SEQL;
  float acc[7] = {};
  for (int k0 = 0; k0 < DINNER; k0 += 64) {
#pragma unroll
    for (int i = 0; i < 8; ++i) {
      int e = tid + i*256;
      int kk = e >> 5, cc = e & 31;
      As[kk][cc] = xc[(size_t)(k0 + kk) * SEQL + l0 + cc];
    }
#pragma unroll
    for (int i = 0; i < 14; ++i) {
      int e = tid + i*256;
      if (e < 64*56) { int kk = e / 56, n = e % 56; Ws[kk][n] = XPW[(size_t)n * DINNER + k0 + kk]; }
    }
    __syncthreads();
#pragma unroll 8
    for (int kk = 0; kk < 64; ++kk) {
      float a = As[kk][ll];
#pragma unroll
      for (int i = 0; i < 7; ++i) acc[i] = fmaf(a, Ws[kk][g*7+i], acc[i]);
    }
    __syncthreads();
  }
  const int t = l0 + ll;
#pragma unroll
  for (int i = 0; i < 7; ++i) {
    int n = g*7 + i;
    if (n < DTRANK)
      DTR[(size_t)((dir*NBATCH + b) * DTRANK + n) * SEQL + t] = acc[i];
    else
      BC[((size_t)(dir*NBATCH + b) * SEQL + t) * 32 + (n - DTRANK)] = acc[i];
  }
}

// ---------------- dt_proj + softplus -> delta ----------------
__global__ __launch_bounds__(256) void k_dtproj(const float* __restrict__ DTR,
    const float* __restrict__ WDT, const float* __restrict__ BDT,
    float* __restrict__ DELTA) {
  __shared__ float S[DTRANK][256];
  const int t0 = blockIdx.x * 256;
  const int d0 = blockIdx.y * 8;
  const int db = blockIdx.z;  // dir*NBATCH + b
  const int tid = threadIdx.x;
  const float* src = DTR + (size_t)(db * DTRANK) * SEQL;
#pragma unroll
  for (int r = 0; r < DTRANK; ++r) S[r][tid] = src[(size_t)r * SEQL + t0 + tid];
  __syncthreads();
#pragma unroll
  for (int i = 0; i < 8; ++i) {
    int d = d0 + i;
    float s = BDT[d];
#pragma unroll
    for (int r = 0; r < DTRANK; ++r) s = fmaf(WDT[d*DTRANK + r], S[r][tid], s);
    float sp = fmaxf(s, 0.f) + log1pf(__expf(-fabsf(s)));
    DELTA[(size_t)(db * DINNER + d) * SEQL + t0 + tid] = sp;
  }
}

// ---------------- chunked scan pass 1: local scan (h0=0), 4 lanes x 4 states ----------------
// outputs: DS[gid] = sum of delta over chunk; HL[gid][16] = local h_end
__global__ __launch_bounds__(256) void k_scan1(const float* __restrict__ DELTA,
    const float* __restrict__ XC, const float* __restrict__ BC,
    const float* __restrict__ Alog, const float* __restrict__ Ablog,
    float* __restrict__ DS, float* __restrict__ HL) {
  const int tid = threadIdx.x;
  const int lk = tid & 3;                         // lane in quad = state quad
  const int gid = blockIdx.x * 64 + (tid >> 2);   // channel-chunk group
  const int c = gid & (NCHUNK - 1);
  const int ch = gid >> 5;                        // /NCHUNK (=32)
  const int d = ch % DINNER;
  const int rest = ch / DINNER;
  const int b = rest & (NBATCH - 1);
  const int dir = rest >> 1;
  const float* Ap = (dir ? Ablog : Alog) + (size_t)d * NSTATE + 4*lk;
  float Av[4];
#pragma unroll
  for (int j = 0; j < 4; ++j) Av[j] = -__expf(Ap[j]);
  const float* dlt_p = DELTA + (size_t)((dir*NBATCH + b) * DINNER + d) * SEQL;
  const float* xc_p  = XC   + (size_t)((dir*NBATCH + b) * DINNER + d) * SEQL;
  const float* bc_p  = BC   + (size_t)(dir*NBATCH + b) * SEQL * 32;
  float h[4] = {0.f, 0.f, 0.f, 0.f};
  float dsum = 0.f;
  const int t0 = c * CHUNK;
#pragma unroll 2
  for (int tb = t0; tb < t0 + CHUNK; tb += 4) {
    const int tl = tb + lk;
    float dltv = dlt_p[tl];
    float xvv  = xc_p[tl];
    float uv   = dltv * xvv;
    dsum += dltv;
#pragma unroll
    for (int k = 0; k < 4; ++k) {
      float dt_t = __shfl(dltv, k, 4);
      float u_t  = __shfl(uv, k, 4);
      float4 b4 = *(const float4*)&bc_p[(tb + k)*32 + 4*lk];
      float bb[4] = {b4.x, b4.y, b4.z, b4.w};
#pragma unroll
      for (int j = 0; j < 4; ++j) {
        float dA = __expf(dt_t * Av[j]);
        h[j] = fmaf(dA, h[j], u_t * bb[j]);
      }
    }
  }
  dsum += __shfl_xor(dsum, 1, 4);
  dsum += __shfl_xor(dsum, 2, 4);
  if (lk == 0) DS[gid] = dsum;
  float4 hv = {h[0], h[1], h[2], h[3]};
  *(float4*)&HL[(size_t)gid * 16 + 4*lk] = hv;
}

// ---------------- fixup: h_start per chunk via P = exp(A * sum_delta) ----------------
__global__ __launch_bounds__(256) void k_scanfix(const float* __restrict__ DS,
    const float* __restrict__ HL, const float* __restrict__ Alog,
    const float* __restrict__ Ablog, float* __restrict__ HS) {
  const int idx = blockIdx.x * 256 + threadIdx.x;  // 0 .. NCH*16-1
  const int ch = idx >> 4;
  const int n = idx & 15;
  const int d = ch % DINNER;
  const int rest = ch / DINNER;
  const int dir = rest >> 1;
  const float Aval = -__expf((dir ? Ablog : Alog)[(size_t)d * NSTATE + n]);
  float h = 0.f;
#pragma unroll
  for (int c = 0; c < NCHUNK; ++c) {
    size_t off = ((size_t)ch * NCHUNK + c) * 16 + n;
    HS[off] = h;
    float p = __expf(DS[(size_t)ch * NCHUNK + c] * Aval);
    h = fmaf(p, h, HL[off]);
  }
}

// ---------------- chunked scan pass 2: recompute with true h_start, emit gated y ----------------
__global__ __launch_bounds__(256) void k_scan2(const float* __restrict__ DELTA,
    const float* __restrict__ XC, const float* __restrict__ BC,
    const float* __restrict__ XZ, const float* __restrict__ Alog,
    const float* __restrict__ Ablog, const float* __restrict__ Dp,
    const float* __restrict__ HS, float* __restrict__ Y) {
  const int tid = threadIdx.x;
  const int lk = tid & 3;
  const int gid = blockIdx.x * 64 + (tid >> 2);
  const int c = gid & (NCHUNK - 1);
  const int ch = gid >> 5;
  const int d = ch % DINNER;
  const int rest = ch / DINNER;
  const int b = rest & (NBATCH - 1);
  const int dir = rest >> 1;
  const float* Ap = (dir ? Ablog : Alog) + (size_t)d * NSTATE + 4*lk;
  float Av[4];
#pragma unroll
  for (int j = 0; j < 4; ++j) Av[j] = -__expf(Ap[j]);
  const float Dd = Dp[d];
  const float* dlt_p = DELTA + (size_t)((dir*NBATCH + b) * DINNER + d) * SEQL;
  const float* xc_p  = XC   + (size_t)((dir*NBATCH + b) * DINNER + d) * SEQL;
  const float* bc_p  = BC   + (size_t)(dir*NBATCH + b) * SEQL * 32;
  const float* z_p   = XZ   + (size_t)(b*(2*DINNER) + DINNER + d) * SEQL;
  float* y_p = Y + (size_t)((dir*NBATCH + b) * DINNER + d) * SEQL;
  float4 h0 = *(const float4*)&HS[(size_t)gid * 16 + 4*lk];
  float h[4] = {h0.x, h0.y, h0.z, h0.w};
  const int t0 = c * CHUNK;
#pragma unroll 2
  for (int tb = t0; tb < t0 + CHUNK; tb += 4) {
    const int tl = tb + lk;
    float dltv = dlt_p[tl];
    float xvv  = xc_p[tl];
    float uv   = dltv * xvv;
    const int to_l = dir ? (SEQL - 1 - tl) : tl;
    float zv = z_p[to_l];
    float gz = silu_f(zv);
    float ysel = 0.f;
#pragma unroll
    for (int k = 0; k < 4; ++k) {
      float dt_t = __shfl(dltv, k, 4);
      float u_t  = __shfl(uv, k, 4);
      float4 b4 = *(const float4*)&bc_p[(tb + k)*32 + 4*lk];
      float4 c4 = *(const float4*)&bc_p[(tb + k)*32 + 16 + 4*lk];
      float bb[4] = {b4.x, b4.y, b4.z, b4.w};
      float cc[4] = {c4.x, c4.y, c4.z, c4.w};
      float py = 0.f;
#pragma unroll
      for (int j = 0; j < 4; ++j) {
        float dA = __expf(dt_t * Av[j]);
        h[j] = fmaf(dA, h[j], u_t * bb[j]);
        py = fmaf(h[j], cc[j], py);
      }
      py += __shfl_xor(py, 1, 4);
      py += __shfl_xor(py, 2, 4);
      if (lk == k) ysel = py;
    }
    float yv = fmaf(xvv, Dd, ysel) * gz;
    y_p[to_l] = yv;
  }
}

// ---------------- out_proj + residual ----------------
__global__ __launch_bounds__(256) void k_outproj(const float* __restrict__ Y,
    const float* __restrict__ WO, const float* __restrict__ X,
    float* __restrict__ OUT) {
  __shared__ __align__(16) float As[16][68];  // [kk][ll] y-sum
  __shared__ __align__(16) float Bs[16][68];  // [kk][oo] WO
  const int bid = blockIdx.x;
  const int b = bid >> 5;
  const int l0 = (bid & 31) * 64;
  const int o0 = blockIdx.y * 64;
  const int tid = threadIdx.x;
  const int to = tid & 15, tl = tid >> 4;
  const float* y0 = Y + (size_t)(b * DINNER) * SEQL;
  const float* y1 = Y + (size_t)((NBATCH + b) * DINNER) * SEQL;
  float acc[4][4] = {};
  const int akk = tid >> 4, alf = (tid & 15) * 4;
  const int boo = tid >> 2, bkf = (tid & 3) * 4;
  for (int k0 = 0; k0 < DINNER; k0 += 16) {
    float4 a0 = *(const float4*)&y0[(size_t)(k0 + akk) * SEQL + l0 + alf];
    float4 a1 = *(const float4*)&y1[(size_t)(k0 + akk) * SEQL + l0 + alf];
    float4 asum = { a0.x+a1.x, a0.y+a1.y, a0.z+a1.z, a0.w+a1.w };
    *(float4*)&As[akk][alf] = asum;
    float4 w = *(const float4*)&WO[(size_t)(o0 + boo) * DINNER + k0 + bkf];
    Bs[bkf+0][boo] = w.x; Bs[bkf+1][boo] = w.y; Bs[bkf+2][boo] = w.z; Bs[bkf+3][boo] = w.w;
    __syncthreads();
#pragma unroll
    for (int kk = 0; kk < 16; ++kk) {
      float4 a = *(const float4*)&As[kk][tl*4];
      float4 b4 = *(const float4*)&Bs[kk][to*4];
      float av[4] = {a.x,a.y,a.z,a.w}, bv[4] = {b4.x,b4.y,b4.z,b4.w};
#pragma unroll
      for (int i=0;i<4;++i)
#pragma unroll
        for (int j=0;j<4;++j) acc[i][j] = fmaf(av[i], bv[j], acc[i][j]);
    }
    __syncthreads();
  }
#pragma unroll
  for (int i=0;i<4;++i) {
    int row = l0 + tl*4 + i;
    size_t off = (size_t)(b*SEQL + row) * DIMX + o0 + to*4;
    float4 xs = *(const float4*)&X[off];
    float4 v = { acc[i][0]+xs.x, acc[i][1]+xs.y, acc[i][2]+xs.z, acc[i][3]+xs.w };
    *(float4*)&OUT[off] = v;
  }
}

extern "C" void kernel_launch(void* const* d_in, const int* in_sizes, int n_in,
                              void* d_out, int out_size, void* d_ws, size_t ws_size,
                              hipStream_t stream) {
  (void)in_sizes; (void)n_in; (void)out_size; (void)ws_size;
  const float* x         = (const float*)d_in[0];
  const float* lin_w     = (const float*)d_in[1];
  const float* lin_b     = (const float*)d_in[2];
  const float* ln_g      = (const float*)d_in[3];
  const float* ln_b      = (const float*)d_in[4];
  const float* in_proj_w = (const float*)d_in[5];
  const float* conv_w    = (const float*)d_in[6];
  const float* conv_b    = (const float*)d_in[7];
  const float* x_proj_w  = (const float*)d_in[8];
  const float* dt_proj_w = (const float*)d_in[9];
  const float* dt_proj_b = (const float*)d_in[10];
  const float* A_log     = (const float*)d_in[11];
  const float* A_b_log   = (const float*)d_in[12];
  const float* Dp        = (const float*)d_in[13];
  const float* out_proj_w= (const float*)d_in[14];
  float* out = (float*)d_out;

  float* ws = (float*)d_ws;
  float* h    = ws;  ws += (size_t)NTOK * DIMX;               // 1.57M floats; dead after k_inproj
  float* xz   = ws;  ws += (size_t)NBATCH * 2*DINNER * SEQL;
  float* xc   = ws;  ws += (size_t)2 * NBATCH * DINNER * SEQL;
  float* dlt  = ws;  ws += (size_t)2 * NBATCH * DINNER * SEQL;
  float* dtr  = ws;  ws += (size_t)2 * NBATCH * DTRANK * SEQL;
  float* bc   = ws;  ws += (size_t)2 * NBATCH * SEQL * 32;
  float* y01  = ws;  ws += (size_t)2 * NBATCH * DINNER * SEQL;
  float* HLb  = ws;  ws += (size_t)NGRP * 16;
  float* DSb  = ws;  ws += (size_t)NGRP;
  float* HSb  = h;   // overlay: NGRP*16 == NTOK*DIMX == 1572864, h dead after k_inproj

  k_lin<<<dim3(NTOK/64, DIMX/64), 256, 0, stream>>>(x, lin_w, lin_b, h);
  k_ln<<<NTOK, 128, 0, stream>>>(h, ln_g, ln_b);
  k_inproj<<<dim3(NBATCH*SEQL/64, 2*DINNER/64), 256, 0, stream>>>(h, in_proj_w, xz);
  k_conv<<<(2*NBATCH*DINNER*SEQL)/256, 256, 0, stream>>>(xz, conv_w, conv_b, xc);
  k_xproj<<<2*NBATCH*(SEQL/32), 256, 0, stream>>>(xc, x_proj_w, dtr, bc);
  k_dtproj<<<dim3(SEQL/256, DINNER/8, 2*NBATCH), 256, 0, stream>>>(dtr, dt_proj_w, dt_proj_b, dlt);
  k_scan1<<<NGRP*4/256, 256, 0, stream>>>(dlt, xc, bc, A_log, A_b_log, DSb, HLb);
  k_scanfix<<<NCH*16/256, 256, 0, stream>>>(DSb, HLb, A_log, A_b_log, HSb);
  k_scan2<<<NGRP*4/256, 256, 0, stream>>>(dlt, xc, bc, xz, A_log, A_b_log, Dp, HSb, y01);
  k_outproj<<<dim3(NBATCH*SEQL/64, DIMX/64), 256, 0, stream>>>(y01, out_proj_w, x, out);
}

// Round 4
// 345.446 us; speedup vs baseline: 3.4534x; 1.1365x over previous
//
#include <hip/hip_runtime.h>
#include <math.h>

#define DIMX 384
#define SEQL 2048
#define NBATCH 2
#define DINNER 768
#define NSTATE 16
#define DTRANK 24
#define NTOK (NBATCH*SEQL)
#define NCHUNK 32
#define CHUNK (SEQL/NCHUNK)   // 64
#define NCH (2*NBATCH*DINNER) // 3072 channels (dir,b,d)
#define NGRP (NCH*NCHUNK)     // 98304 channel-chunk groups
#define KSPL 4                // xproj K-split
#define KS (DINNER/KSPL)      // 192

__device__ __forceinline__ float silu_f(float x) {
  return x / (1.f + __expf(-x));
}

// ---------------- GEMM1: H[m][j] = sum_k X[m][k]*W[j][k] + bias[j] ----------------
__global__ __launch_bounds__(256) void k_lin(const float* __restrict__ X,
    const float* __restrict__ W, const float* __restrict__ bias,
    float* __restrict__ H) {
  __shared__ __align__(16) float As[16][68];
  __shared__ __align__(16) float Bs[16][68];
  const int m0 = blockIdx.x * 64;
  const int j0 = blockIdx.y * 64;
  const int tid = threadIdx.x;
  const int tj = tid & 15, tm = tid >> 4;
  const int lrow = tid >> 2, lkf = (tid & 3) * 4;
  float acc[4][4] = {};
  for (int k0 = 0; k0 < DIMX; k0 += 16) {
    float4 va = *(const float4*)&X[(size_t)(m0 + lrow) * DIMX + k0 + lkf];
    float4 vb = *(const float4*)&W[(size_t)(j0 + lrow) * DIMX + k0 + lkf];
    As[lkf+0][lrow] = va.x; As[lkf+1][lrow] = va.y; As[lkf+2][lrow] = va.z; As[lkf+3][lrow] = va.w;
    Bs[lkf+0][lrow] = vb.x; Bs[lkf+1][lrow] = vb.y; Bs[lkf+2][lrow] = vb.z; Bs[lkf+3][lrow] = vb.w;
    __syncthreads();
#pragma unroll
    for (int kk = 0; kk < 16; ++kk) {
      float4 a = *(const float4*)&As[kk][tm*4];
      float4 b = *(const float4*)&Bs[kk][tj*4];
      float av[4] = {a.x,a.y,a.z,a.w}, bv[4] = {b.x,b.y,b.z,b.w};
#pragma unroll
      for (int i=0;i<4;++i)
#pragma unroll
        for (int j=0;j<4;++j) acc[i][j] = fmaf(av[i], bv[j], acc[i][j]);
    }
    __syncthreads();
  }
  float4 bb = *(const float4*)&bias[j0 + tj*4];
  float bv4[4] = {bb.x,bb.y,bb.z,bb.w};
#pragma unroll
  for (int i=0;i<4;++i) {
    float4 v = { acc[i][0]+bv4[0], acc[i][1]+bv4[1], acc[i][2]+bv4[2], acc[i][3]+bv4[3] };
    *(float4*)&H[(size_t)(m0 + tm*4 + i) * DIMX + j0 + tj*4] = v;
  }
}

// ---------------- LayerNorm + ReLU (in place on H) ----------------
__global__ __launch_bounds__(128) void k_ln(float* __restrict__ H,
    const float* __restrict__ g, const float* __restrict__ bt) {
  const int tok = blockIdx.x;
  float* row = H + (size_t)tok * DIMX;
  const int tid = threadIdx.x;
  float v[3]; float s = 0.f, ss = 0.f;
#pragma unroll
  for (int i = 0; i < 3; ++i) { v[i] = row[tid + i*128]; s += v[i]; ss += v[i]*v[i]; }
  for (int o = 32; o; o >>= 1) { s += __shfl_down(s, o); ss += __shfl_down(ss, o); }
  __shared__ float red[4];
  if ((tid & 63) == 0) { red[(tid>>6)*2] = s; red[(tid>>6)*2+1] = ss; }
  __syncthreads();
  float S = red[0] + red[2], SS = red[1] + red[3];
  float mu = S / DIMX;
  float var = SS / DIMX - mu * mu;
  float inv = rsqrtf(var + 1e-5f);
#pragma unroll
  for (int i = 0; i < 3; ++i) {
    int j = tid + i*128;
    float t = (v[i] - mu) * inv * g[j] + bt[j];
    row[j] = t > 0.f ? t : 0.f;
  }
}

// ---------------- GEMM2: XZ[b][c][l] = sum_k H[b][l][k]*W2[c][k] ----------------
__global__ __launch_bounds__(256) void k_inproj(const float* __restrict__ H,
    const float* __restrict__ W2, float* __restrict__ XZ) {
  __shared__ __align__(16) float Cs[16][68];
  __shared__ __align__(16) float Ls[16][68];
  const int bid = blockIdx.x;
  const int b = bid >> 5;
  const int l0 = (bid & 31) * 64;
  const int c0 = blockIdx.y * 64;
  const int tid = threadIdx.x;
  const int tl = tid & 15, tc = tid >> 4;
  const int lrow = tid >> 2, lkf = (tid & 3) * 4;
  float acc[4][4] = {};
  for (int k0 = 0; k0 < DIMX; k0 += 16) {
    float4 vc = *(const float4*)&W2[(size_t)(c0 + lrow) * DIMX + k0 + lkf];
    float4 vl = *(const float4*)&H[(size_t)(b*SEQL + l0 + lrow) * DIMX + k0 + lkf];
    Cs[lkf+0][lrow] = vc.x; Cs[lkf+1][lrow] = vc.y; Cs[lkf+2][lrow] = vc.z; Cs[lkf+3][lrow] = vc.w;
    Ls[lkf+0][lrow] = vl.x; Ls[lkf+1][lrow] = vl.y; Ls[lkf+2][lrow] = vl.z; Ls[lkf+3][lrow] = vl.w;
    __syncthreads();
#pragma unroll
    for (int kk = 0; kk < 16; ++kk) {
      float4 a = *(const float4*)&Cs[kk][tc*4];
      float4 b4 = *(const float4*)&Ls[kk][tl*4];
      float av[4] = {a.x,a.y,a.z,a.w}, bv[4] = {b4.x,b4.y,b4.z,b4.w};
#pragma unroll
      for (int i=0;i<4;++i)
#pragma unroll
        for (int j=0;j<4;++j) acc[i][j] = fmaf(av[i], bv[j], acc[i][j]);
    }
    __syncthreads();
  }
#pragma unroll
  for (int i=0;i<4;++i) {
    float4 v = { acc[i][0], acc[i][1], acc[i][2], acc[i][3] };
    *(float4*)&XZ[(size_t)(b*(2*DINNER) + c0 + tc*4 + i) * SEQL + l0 + tl*4] = v;
  }
}

// ---------------- causal depthwise conv + silu (both directions) ----------------
__global__ __launch_bounds__(256) void k_conv(const float* __restrict__ XZ,
    const float* __restrict__ cw, const float* __restrict__ cb,
    float* __restrict__ XC) {
  const int idx = blockIdx.x * 256 + threadIdx.x;  // over 2*NB*DI*L
  const int t = idx & (SEQL - 1);
  const int c = idx >> 11;
  const int d = c % DINNER;
  const int bb = c / DINNER;
  const int b = bb & (NBATCH - 1);
  const int dir = bb >> 1;
  const float* row = XZ + (size_t)(b*(2*DINNER) + d) * SEQL;
  float s = cb[d];
  const float w0 = cw[d*4+0], w1 = cw[d*4+1], w2 = cw[d*4+2], w3 = cw[d*4+3];
  if (dir == 0) {
    if (t >= 3) s += w0 * row[t-3];
    if (t >= 2) s += w1 * row[t-2];
    if (t >= 1) s += w2 * row[t-1];
    s += w3 * row[t];
  } else {
    int base = SEQL - 1 - t;
    if (base + 3 < SEQL) s += w0 * row[base+3];
    if (base + 2 < SEQL) s += w1 * row[base+2];
    if (base + 1 < SEQL) s += w2 * row[base+1];
    s += w3 * row[base];
  }
  XC[idx] = silu_f(s);
}

// ---------------- x_proj split-K partial: PART[ks][db][n][t] ----------------
__global__ __launch_bounds__(256) void k_xproj_part(const float* __restrict__ XC,
    const float* __restrict__ XPW, float* __restrict__ PART) {
  __shared__ float As[64][33];
  __shared__ float Ws[64][57];
  const int l0 = blockIdx.x * 32;
  const int ks = blockIdx.y;
  const int db = blockIdx.z;          // dir*NBATCH + b
  const int tid = threadIdx.x;
  const int ll = tid & 31, g = tid >> 5;  // 8 groups x 7 outputs
  const float* xc = XC + (size_t)db * DINNER * SEQL;
  float acc[7] = {};
  const int kbase = ks * KS;
  for (int k0 = kbase; k0 < kbase + KS; k0 += 64) {
#pragma unroll
    for (int i = 0; i < 8; ++i) {
      int e = tid + i*256;
      int kk = e >> 5, cc = e & 31;
      As[kk][cc] = xc[(size_t)(k0 + kk) * SEQL + l0 + cc];
    }
#pragma unroll
    for (int i = 0; i < 14; ++i) {
      int e = tid + i*256;
      if (e < 64*56) { int kk = e / 56, n = e % 56; Ws[kk][n] = XPW[(size_t)n * DINNER + k0 + kk]; }
    }
    __syncthreads();
#pragma unroll 8
    for (int kk = 0; kk < 64; ++kk) {
      float a = As[kk][ll];
#pragma unroll
      for (int i = 0; i < 7; ++i) acc[i] = fmaf(a, Ws[kk][g*7+i], acc[i]);
    }
    __syncthreads();
  }
#pragma unroll
  for (int i = 0; i < 7; ++i) {
    int n = g*7 + i;
    PART[((size_t)(ks*4 + db) * 56 + n) * SEQL + l0 + ll] = acc[i];
  }
}

// ---------------- x_proj reduce: sum partials -> DTR / BC layouts ----------------
__global__ __launch_bounds__(256) void k_xred(const float* __restrict__ PART,
    float* __restrict__ DTR, float* __restrict__ BC) {
  const int idx = blockIdx.x * 256 + threadIdx.x;  // over 4*56*SEQL
  const int db = idx / (56 * SEQL);
  const int r  = idx % (56 * SEQL);
  const int n  = r / SEQL;
  const int t  = r % SEQL;
  float s = 0.f;
#pragma unroll
  for (int ks = 0; ks < KSPL; ++ks)
    s += PART[((size_t)(ks*4 + db) * 56 + n) * SEQL + t];
  if (n < DTRANK)
    DTR[((size_t)db * DTRANK + n) * SEQL + t] = s;
  else
    BC[((size_t)db * SEQL + t) * 32 + (n - DTRANK)] = s;
}

// ---------------- dt_proj + softplus -> delta ----------------
__global__ __launch_bounds__(256) void k_dtproj(const float* __restrict__ DTR,
    const float* __restrict__ WDT, const float* __restrict__ BDT,
    float* __restrict__ DELTA) {
  __shared__ float S[DTRANK][256];
  const int t0 = blockIdx.x * 256;
  const int d0 = blockIdx.y * 8;
  const int db = blockIdx.z;  // dir*NBATCH + b
  const int tid = threadIdx.x;
  const float* src = DTR + (size_t)(db * DTRANK) * SEQL;
#pragma unroll
  for (int r = 0; r < DTRANK; ++r) S[r][tid] = src[(size_t)r * SEQL + t0 + tid];
  __syncthreads();
#pragma unroll
  for (int i = 0; i < 8; ++i) {
    int d = d0 + i;
    float s = BDT[d];
#pragma unroll
    for (int r = 0; r < DTRANK; ++r) s = fmaf(WDT[d*DTRANK + r], S[r][tid], s);
    float sp = fmaxf(s, 0.f) + log1pf(__expf(-fabsf(s)));
    DELTA[(size_t)(db * DINNER + d) * SEQL + t0 + tid] = sp;
  }
}

// ---------------- chunked scan pass 1: local scan (h0=0), 4 lanes x 4 states ----------------
__global__ __launch_bounds__(256) void k_scan1(const float* __restrict__ DELTA,
    const float* __restrict__ XC, const float* __restrict__ BC,
    const float* __restrict__ Alog, const float* __restrict__ Ablog,
    float* __restrict__ DS, float* __restrict__ HL) {
  const int tid = threadIdx.x;
  const int lk = tid & 3;                         // lane in quad = state quad
  const int gid = blockIdx.x * 64 + (tid >> 2);   // channel-chunk group
  const int c = gid & (NCHUNK - 1);
  const int ch = gid >> 5;                        // /NCHUNK (=32)
  const int d = ch % DINNER;
  const int rest = ch / DINNER;
  const int b = rest & (NBATCH - 1);
  const int dir = rest >> 1;
  const float* Ap = (dir ? Ablog : Alog) + (size_t)d * NSTATE + 4*lk;
  float Av[4];
#pragma unroll
  for (int j = 0; j < 4; ++j) Av[j] = -__expf(Ap[j]);
  const float* dlt_p = DELTA + (size_t)((dir*NBATCH + b) * DINNER + d) * SEQL;
  const float* xc_p  = XC   + (size_t)((dir*NBATCH + b) * DINNER + d) * SEQL;
  const float* bc_p  = BC   + (size_t)(dir*NBATCH + b) * SEQL * 32;
  float h[4] = {0.f, 0.f, 0.f, 0.f};
  float dsum = 0.f;
  const int t0 = c * CHUNK;
#pragma unroll 2
  for (int tb = t0; tb < t0 + CHUNK; tb += 4) {
    const int tl = tb + lk;
    float dltv = dlt_p[tl];
    float xvv  = xc_p[tl];
    float uv   = dltv * xvv;
    dsum += dltv;
#pragma unroll
    for (int k = 0; k < 4; ++k) {
      float dt_t = __shfl(dltv, k, 4);
      float u_t  = __shfl(uv, k, 4);
      float4 b4 = *(const float4*)&bc_p[(tb + k)*32 + 4*lk];
      float bb[4] = {b4.x, b4.y, b4.z, b4.w};
#pragma unroll
      for (int j = 0; j < 4; ++j) {
        float dA = __expf(dt_t * Av[j]);
        h[j] = fmaf(dA, h[j], u_t * bb[j]);
      }
    }
  }
  dsum += __shfl_xor(dsum, 1, 4);
  dsum += __shfl_xor(dsum, 2, 4);
  if (lk == 0) DS[gid] = dsum;
  float4 hv = {h[0], h[1], h[2], h[3]};
  *(float4*)&HL[(size_t)gid * 16 + 4*lk] = hv;
}

// ---------------- fixup: h_start per chunk via P = exp(A * sum_delta) ----------------
__global__ __launch_bounds__(256) void k_scanfix(const float* __restrict__ DS,
    const float* __restrict__ HL, const float* __restrict__ Alog,
    const float* __restrict__ Ablog, float* __restrict__ HS) {
  const int idx = blockIdx.x * 256 + threadIdx.x;  // 0 .. NCH*16-1
  const int ch = idx >> 4;
  const int n = idx & 15;
  const int d = ch % DINNER;
  const int rest = ch / DINNER;
  const int dir = rest >> 1;
  const float Aval = -__expf((dir ? Ablog : Alog)[(size_t)d * NSTATE + n]);
  float h = 0.f;
#pragma unroll
  for (int c = 0; c < NCHUNK; ++c) {
    size_t off = ((size_t)ch * NCHUNK + c) * 16 + n;
    HS[off] = h;
    float p = __expf(DS[(size_t)ch * NCHUNK + c] * Aval);
    h = fmaf(p, h, HL[off]);
  }
}

// ---------------- chunked scan pass 2: recompute with true h_start, emit gated y ----------------
__global__ __launch_bounds__(256) void k_scan2(const float* __restrict__ DELTA,
    const float* __restrict__ XC, const float* __restrict__ BC,
    const float* __restrict__ XZ, const float* __restrict__ Alog,
    const float* __restrict__ Ablog, const float* __restrict__ Dp,
    const float* __restrict__ HS, float* __restrict__ Y) {
  const int tid = threadIdx.x;
  const int lk = tid & 3;
  const int gid = blockIdx.x * 64 + (tid >> 2);
  const int c = gid & (NCHUNK - 1);
  const int ch = gid >> 5;
  const int d = ch % DINNER;
  const int rest = ch / DINNER;
  const int b = rest & (NBATCH - 1);
  const int dir = rest >> 1;
  const float* Ap = (dir ? Ablog : Alog) + (size_t)d * NSTATE + 4*lk;
  float Av[4];
#pragma unroll
  for (int j = 0; j < 4; ++j) Av[j] = -__expf(Ap[j]);
  const float Dd = Dp[d];
  const float* dlt_p = DELTA + (size_t)((dir*NBATCH + b) * DINNER + d) * SEQL;
  const float* xc_p  = XC   + (size_t)((dir*NBATCH + b) * DINNER + d) * SEQL;
  const float* bc_p  = BC   + (size_t)(dir*NBATCH + b) * SEQL * 32;
  const float* z_p   = XZ   + (size_t)(b*(2*DINNER) + DINNER + d) * SEQL;
  float* y_p = Y + (size_t)((dir*NBATCH + b) * DINNER + d) * SEQL;
  float4 h0 = *(const float4*)&HS[(size_t)gid * 16 + 4*lk];
  float h[4] = {h0.x, h0.y, h0.z, h0.w};
  const int t0 = c * CHUNK;
#pragma unroll 2
  for (int tb = t0; tb < t0 + CHUNK; tb += 4) {
    const int tl = tb + lk;
    float dltv = dlt_p[tl];
    float xvv  = xc_p[tl];
    float uv   = dltv * xvv;
    const int to_l = dir ? (SEQL - 1 - tl) : tl;
    float zv = z_p[to_l];
    float gz = silu_f(zv);
    float ysel = 0.f;
#pragma unroll
    for (int k = 0; k < 4; ++k) {
      float dt_t = __shfl(dltv, k, 4);
      float u_t  = __shfl(uv, k, 4);
      float4 b4 = *(const float4*)&bc_p[(tb + k)*32 + 4*lk];
      float4 c4 = *(const float4*)&bc_p[(tb + k)*32 + 16 + 4*lk];
      float bb[4] = {b4.x, b4.y, b4.z, b4.w};
      float cc[4] = {c4.x, c4.y, c4.z, c4.w};
      float py = 0.f;
#pragma unroll
      for (int j = 0; j < 4; ++j) {
        float dA = __expf(dt_t * Av[j]);
        h[j] = fmaf(dA, h[j], u_t * bb[j]);
        py = fmaf(h[j], cc[j], py);
      }
      py += __shfl_xor(py, 1, 4);
      py += __shfl_xor(py, 2, 4);
      if (lk == k) ysel = py;
    }
    float yv = fmaf(xvv, Dd, ysel) * gz;
    y_p[to_l] = yv;
  }
}

// ---------------- out_proj + residual ----------------
__global__ __launch_bounds__(256) void k_outproj(const float* __restrict__ Y,
    const float* __restrict__ WO, const float* __restrict__ X,
    float* __restrict__ OUT) {
  __shared__ __align__(16) float As[16][68];  // [kk][ll] y-sum
  __shared__ __align__(16) float Bs[16][68];  // [kk][oo] WO
  const int bid = blockIdx.x;
  const int b = bid >> 5;
  const int l0 = (bid & 31) * 64;
  const int o0 = blockIdx.y * 64;
  const int tid = threadIdx.x;
  const int to = tid & 15, tl = tid >> 4;
  const float* y0 = Y + (size_t)(b * DINNER) * SEQL;
  const float* y1 = Y + (size_t)((NBATCH + b) * DINNER) * SEQL;
  float acc[4][4] = {};
  const int akk = tid >> 4, alf = (tid & 15) * 4;
  const int boo = tid >> 2, bkf = (tid & 3) * 4;
  for (int k0 = 0; k0 < DINNER; k0 += 16) {
    float4 a0 = *(const float4*)&y0[(size_t)(k0 + akk) * SEQL + l0 + alf];
    float4 a1 = *(const float4*)&y1[(size_t)(k0 + akk) * SEQL + l0 + alf];
    float4 asum = { a0.x+a1.x, a0.y+a1.y, a0.z+a1.z, a0.w+a1.w };
    *(float4*)&As[akk][alf] = asum;
    float4 w = *(const float4*)&WO[(size_t)(o0 + boo) * DINNER + k0 + bkf];
    Bs[bkf+0][boo] = w.x; Bs[bkf+1][boo] = w.y; Bs[bkf+2][boo] = w.z; Bs[bkf+3][boo] = w.w;
    __syncthreads();
#pragma unroll
    for (int kk = 0; kk < 16; ++kk) {
      float4 a = *(const float4*)&As[kk][tl*4];
      float4 b4 = *(const float4*)&Bs[kk][to*4];
      float av[4] = {a.x,a.y,a.z,a.w}, bv[4] = {b4.x,b4.y,b4.z,b4.w};
#pragma unroll
      for (int i=0;i<4;++i)
#pragma unroll
        for (int j=0;j<4;++j) acc[i][j] = fmaf(av[i], bv[j], acc[i][j]);
    }
    __syncthreads();
  }
#pragma unroll
  for (int i=0;i<4;++i) {
    int row = l0 + tl*4 + i;
    size_t off = (size_t)(b*SEQL + row) * DIMX + o0 + to*4;
    float4 xs = *(const float4*)&X[off];
    float4 v = { acc[i][0]+xs.x, acc[i][1]+xs.y, acc[i][2]+xs.z, acc[i][3]+xs.w };
    *(float4*)&OUT[off] = v;
  }
}

extern "C" void kernel_launch(void* const* d_in, const int* in_sizes, int n_in,
                              void* d_out, int out_size, void* d_ws, size_t ws_size,
                              hipStream_t stream) {
  (void)in_sizes; (void)n_in; (void)out_size; (void)ws_size;
  const float* x         = (const float*)d_in[0];
  const float* lin_w     = (const float*)d_in[1];
  const float* lin_b     = (const float*)d_in[2];
  const float* ln_g      = (const float*)d_in[3];
  const float* ln_b      = (const float*)d_in[4];
  const float* in_proj_w = (const float*)d_in[5];
  const float* conv_w    = (const float*)d_in[6];
  const float* conv_b    = (const float*)d_in[7];
  const float* x_proj_w  = (const float*)d_in[8];
  const float* dt_proj_w = (const float*)d_in[9];
  const float* dt_proj_b = (const float*)d_in[10];
  const float* A_log     = (const float*)d_in[11];
  const float* A_b_log   = (const float*)d_in[12];
  const float* Dp        = (const float*)d_in[13];
  const float* out_proj_w= (const float*)d_in[14];
  float* out = (float*)d_out;

  float* ws = (float*)d_ws;
  float* h    = ws;  ws += (size_t)NTOK * DIMX;               // dead after k_inproj -> reused as HS
  float* xz   = ws;  ws += (size_t)NBATCH * 2*DINNER * SEQL;
  float* xc   = ws;  ws += (size_t)2 * NBATCH * DINNER * SEQL;
  float* dlt  = ws;  ws += (size_t)2 * NBATCH * DINNER * SEQL;
  float* dtr  = ws;  ws += (size_t)2 * NBATCH * DTRANK * SEQL;
  float* bc   = ws;  ws += (size_t)2 * NBATCH * SEQL * 32;
  float* y01  = ws;  ws += (size_t)2 * NBATCH * DINNER * SEQL;
  float* HLb  = ws;  ws += (size_t)NGRP * 16;
  float* DSb  = ws;  ws += (size_t)NGRP;
  float* HSb  = h;    // overlay: NGRP*16 == NTOK*DIMX, h dead after k_inproj
  float* PART = y01;  // overlay: KSPL*4*56*SEQL (1.84M) <= y01 (12.6M), y01 written later by k_scan2

  k_lin<<<dim3(NTOK/64, DIMX/64), 256, 0, stream>>>(x, lin_w, lin_b, h);
  k_ln<<<NTOK, 128, 0, stream>>>(h, ln_g, ln_b);
  k_inproj<<<dim3(NBATCH*SEQL/64, 2*DINNER/64), 256, 0, stream>>>(h, in_proj_w, xz);
  k_conv<<<(2*NBATCH*DINNER*SEQL)/256, 256, 0, stream>>>(xz, conv_w, conv_b, xc);
  k_xproj_part<<<dim3(SEQL/32, KSPL, 2*NBATCH), 256, 0, stream>>>(xc, x_proj_w, PART);
  k_xred<<<(2*NBATCH*56*SEQL)/256, 256, 0, stream>>>(PART, dtr, bc);
  k_dtproj<<<dim3(SEQL/256, DINNER/8, 2*NBATCH), 256, 0, stream>>>(dtr, dt_proj_w, dt_proj_b, dlt);
  k_scan1<<<NGRP*4/256, 256, 0, stream>>>(dlt, xc, bc, A_log, A_b_log, DSb, HLb);
  k_scanfix<<<NCH*16/256, 256, 0, stream>>>(DSb, HLb, A_log, A_b_log, HSb);
  k_scan2<<<NGRP*4/256, 256, 0, stream>>>(dlt, xc, bc, xz, A_log, A_b_log, Dp, HSb, y01);
  k_outproj<<<dim3(NBATCH*SEQL/64, DIMX/64), 256, 0, stream>>>(y01, out_proj_w, x, out);
}

// Round 5
// 251.864 us; speedup vs baseline: 4.7365x; 1.3716x over previous
//
#include <hip/hip_runtime.h>
#include <math.h>

#define DIMX 384
#define SEQL 2048
#define NBATCH 2
#define DINNER 768
#define NSTATE 16
#define DTRANK 24
#define NTOK (NBATCH*SEQL)
#define NCHUNK 32
#define CHUNK (SEQL/NCHUNK)   // 64
#define NCH (2*NBATCH*DINNER) // 3072 channels (dir,b,d)
#define NGRP (NCH*NCHUNK)     // 98304 channel-chunk groups
#define KSPL 4                // xproj K-split
#define KS (DINNER/KSPL)      // 192

typedef __attribute__((ext_vector_type(8))) short bf16x8;
typedef __attribute__((ext_vector_type(8))) unsigned short u16x8;
typedef __attribute__((ext_vector_type(4))) float f32x4;

__device__ __forceinline__ float silu_f(float x) {
  return x / (1.f + __expf(-x));
}

__device__ __forceinline__ unsigned short f2bf(float f) {
  unsigned int u = __float_as_uint(f);
  unsigned int r = u + 0x7fffu + ((u >> 16) & 1u);   // round-to-nearest-even
  return (unsigned short)(r >> 16);
}

// ---------------- GEMM1 (bf16 MFMA): H[m][j] = sum_k X[m][k]*W[j][k] + bias[j] ----------------
__global__ __launch_bounds__(256) void k_lin(const float* __restrict__ X,
    const float* __restrict__ W, const float* __restrict__ bias,
    float* __restrict__ H) {
  __shared__ unsigned short LA[64][40];
  __shared__ unsigned short LB[64][40];
  const int m0 = blockIdx.x * 64, n0 = blockIdx.y * 64;
  const int tid = threadIdx.x, lane = tid & 63, w = tid >> 6;
  const int wm = (w >> 1) * 32, wn = (w & 1) * 32;
  const int fr = lane & 15, fg = lane >> 4;
  const int srow = tid >> 2, skg = (tid & 3) * 8;
  f32x4 acc[2][2] = {};
  for (int k0 = 0; k0 < DIMX; k0 += 32) {
    const float* ga = &X[(size_t)(m0 + srow) * DIMX + k0 + skg];
    const float* gb = &W[(size_t)(n0 + srow) * DIMX + k0 + skg];
    float4 a1 = *(const float4*)ga, a2 = *(const float4*)(ga + 4);
    float4 b1 = *(const float4*)gb, b2 = *(const float4*)(gb + 4);
    u16x8 va, vb;
    va[0]=f2bf(a1.x); va[1]=f2bf(a1.y); va[2]=f2bf(a1.z); va[3]=f2bf(a1.w);
    va[4]=f2bf(a2.x); va[5]=f2bf(a2.y); va[6]=f2bf(a2.z); va[7]=f2bf(a2.w);
    vb[0]=f2bf(b1.x); vb[1]=f2bf(b1.y); vb[2]=f2bf(b1.z); vb[3]=f2bf(b1.w);
    vb[4]=f2bf(b2.x); vb[5]=f2bf(b2.y); vb[6]=f2bf(b2.z); vb[7]=f2bf(b2.w);
    *(u16x8*)&LA[srow][skg] = va;
    *(u16x8*)&LB[srow][skg] = vb;
    __syncthreads();
    bf16x8 af[2], bfr[2];
    af[0]  = *(const bf16x8*)&LA[wm + fr][fg*8];
    af[1]  = *(const bf16x8*)&LA[wm + 16 + fr][fg*8];
    bfr[0] = *(const bf16x8*)&LB[wn + fr][fg*8];
    bfr[1] = *(const bf16x8*)&LB[wn + 16 + fr][fg*8];
#pragma unroll
    for (int i = 0; i < 2; ++i)
#pragma unroll
      for (int j = 0; j < 2; ++j)
        acc[i][j] = __builtin_amdgcn_mfma_f32_16x16x32_bf16(af[i], bfr[j], acc[i][j], 0, 0, 0);
    __syncthreads();
  }
#pragma unroll
  for (int i = 0; i < 2; ++i)
#pragma unroll
    for (int j = 0; j < 2; ++j)
#pragma unroll
      for (int r = 0; r < 4; ++r) {
        int m = m0 + wm + i*16 + fg*4 + r;
        int n = n0 + wn + j*16 + fr;
        H[(size_t)m * DIMX + n] = acc[i][j][r] + bias[n];
      }
}

// ---------------- LayerNorm + ReLU (in place on H) ----------------
__global__ __launch_bounds__(128) void k_ln(float* __restrict__ H,
    const float* __restrict__ g, const float* __restrict__ bt) {
  const int tok = blockIdx.x;
  float* row = H + (size_t)tok * DIMX;
  const int tid = threadIdx.x;
  float v[3]; float s = 0.f, ss = 0.f;
#pragma unroll
  for (int i = 0; i < 3; ++i) { v[i] = row[tid + i*128]; s += v[i]; ss += v[i]*v[i]; }
  for (int o = 32; o; o >>= 1) { s += __shfl_down(s, o); ss += __shfl_down(ss, o); }
  __shared__ float red[4];
  if ((tid & 63) == 0) { red[(tid>>6)*2] = s; red[(tid>>6)*2+1] = ss; }
  __syncthreads();
  float S = red[0] + red[2], SS = red[1] + red[3];
  float mu = S / DIMX;
  float var = SS / DIMX - mu * mu;
  float inv = rsqrtf(var + 1e-5f);
#pragma unroll
  for (int i = 0; i < 3; ++i) {
    int j = tid + i*128;
    float t = (v[i] - mu) * inv * g[j] + bt[j];
    row[j] = t > 0.f ? t : 0.f;
  }
}

// ---------------- GEMM2 (bf16 MFMA): XZ[b][c][l] = sum_k H[b][l][k]*W2[c][k] ----------------
__global__ __launch_bounds__(256) void k_inproj(const float* __restrict__ H,
    const float* __restrict__ W2, float* __restrict__ XZ) {
  __shared__ unsigned short LA[64][40];   // [c][k]
  __shared__ unsigned short LB[64][40];   // [tok][k]
  const int n0 = blockIdx.x * 64;         // token tile
  const int m0 = blockIdx.y * 64;         // channel tile
  const int tid = threadIdx.x, lane = tid & 63, w = tid >> 6;
  const int wm = (w >> 1) * 32, wn = (w & 1) * 32;
  const int fr = lane & 15, fg = lane >> 4;
  const int srow = tid >> 2, skg = (tid & 3) * 8;
  f32x4 acc[2][2] = {};
  for (int k0 = 0; k0 < DIMX; k0 += 32) {
    const float* ga = &W2[(size_t)(m0 + srow) * DIMX + k0 + skg];
    const float* gb = &H[(size_t)(n0 + srow) * DIMX + k0 + skg];
    float4 a1 = *(const float4*)ga, a2 = *(const float4*)(ga + 4);
    float4 b1 = *(const float4*)gb, b2 = *(const float4*)(gb + 4);
    u16x8 va, vb;
    va[0]=f2bf(a1.x); va[1]=f2bf(a1.y); va[2]=f2bf(a1.z); va[3]=f2bf(a1.w);
    va[4]=f2bf(a2.x); va[5]=f2bf(a2.y); va[6]=f2bf(a2.z); va[7]=f2bf(a2.w);
    vb[0]=f2bf(b1.x); vb[1]=f2bf(b1.y); vb[2]=f2bf(b1.z); vb[3]=f2bf(b1.w);
    vb[4]=f2bf(b2.x); vb[5]=f2bf(b2.y); vb[6]=f2bf(b2.z); vb[7]=f2bf(b2.w);
    *(u16x8*)&LA[srow][skg] = va;
    *(u16x8*)&LB[srow][skg] = vb;
    __syncthreads();
    bf16x8 af[2], bfr[2];
    af[0]  = *(const bf16x8*)&LA[wm + fr][fg*8];
    af[1]  = *(const bf16x8*)&LA[wm + 16 + fr][fg*8];
    bfr[0] = *(const bf16x8*)&LB[wn + fr][fg*8];
    bfr[1] = *(const bf16x8*)&LB[wn + 16 + fr][fg*8];
#pragma unroll
    for (int i = 0; i < 2; ++i)
#pragma unroll
      for (int j = 0; j < 2; ++j)
        acc[i][j] = __builtin_amdgcn_mfma_f32_16x16x32_bf16(af[i], bfr[j], acc[i][j], 0, 0, 0);
    __syncthreads();
  }
  const int b = n0 >> 11;
  const int lbase = n0 & (SEQL - 1);
#pragma unroll
  for (int i = 0; i < 2; ++i)
#pragma unroll
    for (int j = 0; j < 2; ++j)
#pragma unroll
      for (int r = 0; r < 4; ++r) {
        int c = m0 + wm + i*16 + fg*4 + r;
        int l = lbase + wn + j*16 + fr;
        XZ[((size_t)(b*(2*DINNER) + c)) * SEQL + l] = acc[i][j][r];
      }
}

// ---------------- causal depthwise conv + silu (both directions) ----------------
__global__ __launch_bounds__(256) void k_conv(const float* __restrict__ XZ,
    const float* __restrict__ cw, const float* __restrict__ cb,
    float* __restrict__ XC) {
  const int idx = blockIdx.x * 256 + threadIdx.x;  // over 2*NB*DI*L
  const int t = idx & (SEQL - 1);
  const int c = idx >> 11;
  const int d = c % DINNER;
  const int bb = c / DINNER;
  const int b = bb & (NBATCH - 1);
  const int dir = bb >> 1;
  const float* row = XZ + (size_t)(b*(2*DINNER) + d) * SEQL;
  float s = cb[d];
  const float w0 = cw[d*4+0], w1 = cw[d*4+1], w2 = cw[d*4+2], w3 = cw[d*4+3];
  if (dir == 0) {
    if (t >= 3) s += w0 * row[t-3];
    if (t >= 2) s += w1 * row[t-2];
    if (t >= 1) s += w2 * row[t-1];
    s += w3 * row[t];
  } else {
    int base = SEQL - 1 - t;
    if (base + 3 < SEQL) s += w0 * row[base+3];
    if (base + 2 < SEQL) s += w1 * row[base+2];
    if (base + 1 < SEQL) s += w2 * row[base+1];
    s += w3 * row[base];
  }
  XC[idx] = silu_f(s);
}

// ---------------- x_proj split-K partial: PART[ks][db][n][t] ----------------
__global__ __launch_bounds__(256) void k_xproj_part(const float* __restrict__ XC,
    const float* __restrict__ XPW, float* __restrict__ PART) {
  __shared__ float As[64][33];
  __shared__ float Ws[64][57];
  const int l0 = blockIdx.x * 32;
  const int ks = blockIdx.y;
  const int db = blockIdx.z;          // dir*NBATCH + b
  const int tid = threadIdx.x;
  const int ll = tid & 31, g = tid >> 5;  // 8 groups x 7 outputs
  const float* xc = XC + (size_t)db * DINNER * SEQL;
  float acc[7] = {};
  const int kbase = ks * KS;
  for (int k0 = kbase; k0 < kbase + KS; k0 += 64) {
#pragma unroll
    for (int i = 0; i < 8; ++i) {
      int e = tid + i*256;
      int kk = e >> 5, cc = e & 31;
      As[kk][cc] = xc[(size_t)(k0 + kk) * SEQL + l0 + cc];
    }
#pragma unroll
    for (int i = 0; i < 14; ++i) {
      int e = tid + i*256;
      if (e < 64*56) { int kk = e / 56, n = e % 56; Ws[kk][n] = XPW[(size_t)n * DINNER + k0 + kk]; }
    }
    __syncthreads();
#pragma unroll 8
    for (int kk = 0; kk < 64; ++kk) {
      float a = As[kk][ll];
#pragma unroll
      for (int i = 0; i < 7; ++i) acc[i] = fmaf(a, Ws[kk][g*7+i], acc[i]);
    }
    __syncthreads();
  }
#pragma unroll
  for (int i = 0; i < 7; ++i) {
    int n = g*7 + i;
    PART[((size_t)(ks*4 + db) * 56 + n) * SEQL + l0 + ll] = acc[i];
  }
}

// ---------------- x_proj reduce: sum partials -> DTR / BC layouts ----------------
__global__ __launch_bounds__(256) void k_xred(const float* __restrict__ PART,
    float* __restrict__ DTR, float* __restrict__ BC) {
  const int idx = blockIdx.x * 256 + threadIdx.x;  // over 4*56*SEQL
  const int db = idx / (56 * SEQL);
  const int r  = idx % (56 * SEQL);
  const int n  = r / SEQL;
  const int t  = r % SEQL;
  float s = 0.f;
#pragma unroll
  for (int ks = 0; ks < KSPL; ++ks)
    s += PART[((size_t)(ks*4 + db) * 56 + n) * SEQL + t];
  if (n < DTRANK)
    DTR[((size_t)db * DTRANK + n) * SEQL + t] = s;
  else
    BC[((size_t)db * SEQL + t) * 32 + (n - DTRANK)] = s;
}

// ---------------- dt_proj + softplus -> delta ----------------
__global__ __launch_bounds__(256) void k_dtproj(const float* __restrict__ DTR,
    const float* __restrict__ WDT, const float* __restrict__ BDT,
    float* __restrict__ DELTA) {
  __shared__ float S[DTRANK][256];
  const int t0 = blockIdx.x * 256;
  const int d0 = blockIdx.y * 8;
  const int db = blockIdx.z;  // dir*NBATCH + b
  const int tid = threadIdx.x;
  const float* src = DTR + (size_t)(db * DTRANK) * SEQL;
#pragma unroll
  for (int r = 0; r < DTRANK; ++r) S[r][tid] = src[(size_t)r * SEQL + t0 + tid];
  __syncthreads();
#pragma unroll
  for (int i = 0; i < 8; ++i) {
    int d = d0 + i;
    float s = BDT[d];
#pragma unroll
    for (int r = 0; r < DTRANK; ++r) s = fmaf(WDT[d*DTRANK + r], S[r][tid], s);
    float sp = fmaxf(s, 0.f) + log1pf(__expf(-fabsf(s)));
    DELTA[(size_t)(db * DINNER + d) * SEQL + t0 + tid] = sp;
  }
}

// ---------------- chunked scan pass 1: local scan (h0=0), 4 lanes x 4 states ----------------
__global__ __launch_bounds__(256) void k_scan1(const float* __restrict__ DELTA,
    const float* __restrict__ XC, const float* __restrict__ BC,
    const float* __restrict__ Alog, const float* __restrict__ Ablog,
    float* __restrict__ DS, float* __restrict__ HL) {
  const int tid = threadIdx.x;
  const int lk = tid & 3;                         // lane in quad = state quad
  const int gid = blockIdx.x * 64 + (tid >> 2);   // channel-chunk group
  const int c = gid & (NCHUNK - 1);
  const int ch = gid >> 5;                        // /NCHUNK (=32)
  const int d = ch % DINNER;
  const int rest = ch / DINNER;
  const int b = rest & (NBATCH - 1);
  const int dir = rest >> 1;
  const float* Ap = (dir ? Ablog : Alog) + (size_t)d * NSTATE + 4*lk;
  float Av[4];
#pragma unroll
  for (int j = 0; j < 4; ++j) Av[j] = -__expf(Ap[j]);
  const float* dlt_p = DELTA + (size_t)((dir*NBATCH + b) * DINNER + d) * SEQL;
  const float* xc_p  = XC   + (size_t)((dir*NBATCH + b) * DINNER + d) * SEQL;
  const float* bc_p  = BC   + (size_t)(dir*NBATCH + b) * SEQL * 32;
  float h[4] = {0.f, 0.f, 0.f, 0.f};
  float dsum = 0.f;
  const int t0 = c * CHUNK;
#pragma unroll 2
  for (int tb = t0; tb < t0 + CHUNK; tb += 4) {
    const int tl = tb + lk;
    float dltv = dlt_p[tl];
    float xvv  = xc_p[tl];
    float uv   = dltv * xvv;
    dsum += dltv;
#pragma unroll
    for (int k = 0; k < 4; ++k) {
      float dt_t = __shfl(dltv, k, 4);
      float u_t  = __shfl(uv, k, 4);
      float4 b4 = *(const float4*)&bc_p[(tb + k)*32 + 4*lk];
      float bb[4] = {b4.x, b4.y, b4.z, b4.w};
#pragma unroll
      for (int j = 0; j < 4; ++j) {
        float dA = __expf(dt_t * Av[j]);
        h[j] = fmaf(dA, h[j], u_t * bb[j]);
      }
    }
  }
  dsum += __shfl_xor(dsum, 1, 4);
  dsum += __shfl_xor(dsum, 2, 4);
  if (lk == 0) DS[gid] = dsum;
  float4 hv = {h[0], h[1], h[2], h[3]};
  *(float4*)&HL[(size_t)gid * 16 + 4*lk] = hv;
}

// ---------------- fixup: h_start per chunk via P = exp(A * sum_delta) ----------------
__global__ __launch_bounds__(256) void k_scanfix(const float* __restrict__ DS,
    const float* __restrict__ HL, const float* __restrict__ Alog,
    const float* __restrict__ Ablog, float* __restrict__ HS) {
  const int idx = blockIdx.x * 256 + threadIdx.x;  // 0 .. NCH*16-1
  const int ch = idx >> 4;
  const int n = idx & 15;
  const int d = ch % DINNER;
  const int rest = ch / DINNER;
  const int dir = rest >> 1;
  const float Aval = -__expf((dir ? Ablog : Alog)[(size_t)d * NSTATE + n]);
  float h = 0.f;
#pragma unroll
  for (int c = 0; c < NCHUNK; ++c) {
    size_t off = ((size_t)ch * NCHUNK + c) * 16 + n;
    HS[off] = h;
    float p = __expf(DS[(size_t)ch * NCHUNK + c] * Aval);
    h = fmaf(p, h, HL[off]);
  }
}

// ---------------- chunked scan pass 2: recompute with true h_start, emit gated y ----------------
__global__ __launch_bounds__(256) void k_scan2(const float* __restrict__ DELTA,
    const float* __restrict__ XC, const float* __restrict__ BC,
    const float* __restrict__ XZ, const float* __restrict__ Alog,
    const float* __restrict__ Ablog, const float* __restrict__ Dp,
    const float* __restrict__ HS, float* __restrict__ Y) {
  const int tid = threadIdx.x;
  const int lk = tid & 3;
  const int gid = blockIdx.x * 64 + (tid >> 2);
  const int c = gid & (NCHUNK - 1);
  const int ch = gid >> 5;
  const int d = ch % DINNER;
  const int rest = ch / DINNER;
  const int b = rest & (NBATCH - 1);
  const int dir = rest >> 1;
  const float* Ap = (dir ? Ablog : Alog) + (size_t)d * NSTATE + 4*lk;
  float Av[4];
#pragma unroll
  for (int j = 0; j < 4; ++j) Av[j] = -__expf(Ap[j]);
  const float Dd = Dp[d];
  const float* dlt_p = DELTA + (size_t)((dir*NBATCH + b) * DINNER + d) * SEQL;
  const float* xc_p  = XC   + (size_t)((dir*NBATCH + b) * DINNER + d) * SEQL;
  const float* bc_p  = BC   + (size_t)(dir*NBATCH + b) * SEQL * 32;
  const float* z_p   = XZ   + (size_t)(b*(2*DINNER) + DINNER + d) * SEQL;
  float* y_p = Y + (size_t)((dir*NBATCH + b) * DINNER + d) * SEQL;
  float4 h0 = *(const float4*)&HS[(size_t)gid * 16 + 4*lk];
  float h[4] = {h0.x, h0.y, h0.z, h0.w};
  const int t0 = c * CHUNK;
#pragma unroll 2
  for (int tb = t0; tb < t0 + CHUNK; tb += 4) {
    const int tl = tb + lk;
    float dltv = dlt_p[tl];
    float xvv  = xc_p[tl];
    float uv   = dltv * xvv;
    const int to_l = dir ? (SEQL - 1 - tl) : tl;
    float zv = z_p[to_l];
    float gz = silu_f(zv);
    float ysel = 0.f;
#pragma unroll
    for (int k = 0; k < 4; ++k) {
      float dt_t = __shfl(dltv, k, 4);
      float u_t  = __shfl(uv, k, 4);
      float4 b4 = *(const float4*)&bc_p[(tb + k)*32 + 4*lk];
      float4 c4 = *(const float4*)&bc_p[(tb + k)*32 + 16 + 4*lk];
      float bb[4] = {b4.x, b4.y, b4.z, b4.w};
      float cc[4] = {c4.x, c4.y, c4.z, c4.w};
      float py = 0.f;
#pragma unroll
      for (int j = 0; j < 4; ++j) {
        float dA = __expf(dt_t * Av[j]);
        h[j] = fmaf(dA, h[j], u_t * bb[j]);
        py = fmaf(h[j], cc[j], py);
      }
      py += __shfl_xor(py, 1, 4);
      py += __shfl_xor(py, 2, 4);
      if (lk == k) ysel = py;
    }
    float yv = fmaf(xvv, Dd, ysel) * gz;
    y_p[to_l] = yv;
  }
}

// ---------------- out_proj (bf16 MFMA) + residual ----------------
// OUT[tok][o] = sum_k (y0[k][tok]+y1[k][tok]) * WO[o][k] + X[tok][o]
__global__ __launch_bounds__(256) void k_outproj(const float* __restrict__ Y,
    const float* __restrict__ WO, const float* __restrict__ X,
    float* __restrict__ OUT) {
  __shared__ unsigned short LA[64][40];   // [tok][k] (transposed stage)
  __shared__ unsigned short LB[64][40];   // [o][k]
  const int m0 = blockIdx.x * 64;         // token tile
  const int n0 = blockIdx.y * 64;         // output-dim tile
  const int tid = threadIdx.x, lane = tid & 63, w = tid >> 6;
  const int wm = (w >> 1) * 32, wn = (w & 1) * 32;
  const int fr = lane & 15, fg = lane >> 4;
  const int b = m0 >> 11, lb = m0 & (SEQL - 1);
  const float* y0 = Y + (size_t)b * DINNER * SEQL;
  const float* y1 = Y + (size_t)(NBATCH + b) * DINNER * SEQL;
  const int kk = tid >> 3, tg = (tid & 7) * 8;   // A staging: 32 k x 8 tok-groups
  const int srow = tid >> 2, skg = (tid & 3) * 8; // B staging
  f32x4 acc[2][2] = {};
  for (int k0 = 0; k0 < DINNER; k0 += 32) {
    const float* p0 = y0 + (size_t)(k0 + kk) * SEQL + lb + tg;
    const float* p1 = y1 + (size_t)(k0 + kk) * SEQL + lb + tg;
    float4 u0 = *(const float4*)p0, u1 = *(const float4*)(p0 + 4);
    float4 v0 = *(const float4*)p1, v1 = *(const float4*)(p1 + 4);
    float s[8] = {u0.x+v0.x, u0.y+v0.y, u0.z+v0.z, u0.w+v0.w,
                  u1.x+v1.x, u1.y+v1.y, u1.z+v1.z, u1.w+v1.w};
#pragma unroll
    for (int i = 0; i < 8; ++i) LA[tg + i][kk] = f2bf(s[i]);
    const float* gb = &WO[(size_t)(n0 + srow) * DINNER + k0 + skg];
    float4 b1 = *(const float4*)gb, b2 = *(const float4*)(gb + 4);
    u16x8 vb;
    vb[0]=f2bf(b1.x); vb[1]=f2bf(b1.y); vb[2]=f2bf(b1.z); vb[3]=f2bf(b1.w);
    vb[4]=f2bf(b2.x); vb[5]=f2bf(b2.y); vb[6]=f2bf(b2.z); vb[7]=f2bf(b2.w);
    *(u16x8*)&LB[srow][skg] = vb;
    __syncthreads();
    bf16x8 af[2], bfr[2];
    af[0]  = *(const bf16x8*)&LA[wm + fr][fg*8];
    af[1]  = *(const bf16x8*)&LA[wm + 16 + fr][fg*8];
    bfr[0] = *(const bf16x8*)&LB[wn + fr][fg*8];
    bfr[1] = *(const bf16x8*)&LB[wn + 16 + fr][fg*8];
#pragma unroll
    for (int i = 0; i < 2; ++i)
#pragma unroll
      for (int j = 0; j < 2; ++j)
        acc[i][j] = __builtin_amdgcn_mfma_f32_16x16x32_bf16(af[i], bfr[j], acc[i][j], 0, 0, 0);
    __syncthreads();
  }
#pragma unroll
  for (int i = 0; i < 2; ++i)
#pragma unroll
    for (int j = 0; j < 2; ++j)
#pragma unroll
      for (int r = 0; r < 4; ++r) {
        int tok = m0 + wm + i*16 + fg*4 + r;
        int o = n0 + wn + j*16 + fr;
        size_t off = (size_t)tok * DIMX + o;
        OUT[off] = acc[i][j][r] + X[off];
      }
}

extern "C" void kernel_launch(void* const* d_in, const int* in_sizes, int n_in,
                              void* d_out, int out_size, void* d_ws, size_t ws_size,
                              hipStream_t stream) {
  (void)in_sizes; (void)n_in; (void)out_size; (void)ws_size;
  const float* x         = (const float*)d_in[0];
  const float* lin_w     = (const float*)d_in[1];
  const float* lin_b     = (const float*)d_in[2];
  const float* ln_g      = (const float*)d_in[3];
  const float* ln_b      = (const float*)d_in[4];
  const float* in_proj_w = (const float*)d_in[5];
  const float* conv_w    = (const float*)d_in[6];
  const float* conv_b    = (const float*)d_in[7];
  const float* x_proj_w  = (const float*)d_in[8];
  const float* dt_proj_w = (const float*)d_in[9];
  const float* dt_proj_b = (const float*)d_in[10];
  const float* A_log     = (const float*)d_in[11];
  const float* A_b_log   = (const float*)d_in[12];
  const float* Dp        = (const float*)d_in[13];
  const float* out_proj_w= (const float*)d_in[14];
  float* out = (float*)d_out;

  float* ws = (float*)d_ws;
  float* h    = ws;  ws += (size_t)NTOK * DIMX;               // dead after k_inproj -> reused as HS
  float* xz   = ws;  ws += (size_t)NBATCH * 2*DINNER * SEQL;
  float* xc   = ws;  ws += (size_t)2 * NBATCH * DINNER * SEQL;
  float* dlt  = ws;  ws += (size_t)2 * NBATCH * DINNER * SEQL;
  float* dtr  = ws;  ws += (size_t)2 * NBATCH * DTRANK * SEQL;
  float* bc   = ws;  ws += (size_t)2 * NBATCH * SEQL * 32;
  float* y01  = ws;  ws += (size_t)2 * NBATCH * DINNER * SEQL;
  float* HLb  = ws;  ws += (size_t)NGRP * 16;
  float* DSb  = ws;  ws += (size_t)NGRP;
  float* HSb  = h;    // overlay: NGRP*16 == NTOK*DIMX, h dead after k_inproj
  float* PART = y01;  // overlay: KSPL*4*56*SEQL (1.84M) <= y01 (12.6M), y01 written later by k_scan2

  k_lin<<<dim3(NTOK/64, DIMX/64), 256, 0, stream>>>(x, lin_w, lin_b, h);
  k_ln<<<NTOK, 128, 0, stream>>>(h, ln_g, ln_b);
  k_inproj<<<dim3(NTOK/64, 2*DINNER/64), 256, 0, stream>>>(h, in_proj_w, xz);
  k_conv<<<(2*NBATCH*DINNER*SEQL)/256, 256, 0, stream>>>(xz, conv_w, conv_b, xc);
  k_xproj_part<<<dim3(SEQL/32, KSPL, 2*NBATCH), 256, 0, stream>>>(xc, x_proj_w, PART);
  k_xred<<<(2*NBATCH*56*SEQL)/256, 256, 0, stream>>>(PART, dtr, bc);
  k_dtproj<<<dim3(SEQL/256, DINNER/8, 2*NBATCH), 256, 0, stream>>>(dtr, dt_proj_w, dt_proj_b, dlt);
  k_scan1<<<NGRP*4/256, 256, 0, stream>>>(dlt, xc, bc, A_log, A_b_log, DSb, HLb);
  k_scanfix<<<NCH*16/256, 256, 0, stream>>>(DSb, HLb, A_log, A_b_log, HSb);
  k_scan2<<<NGRP*4/256, 256, 0, stream>>>(dlt, xc, bc, xz, A_log, A_b_log, Dp, HSb, y01);
  k_outproj<<<dim3(NTOK/64, DIMX/64), 256, 0, stream>>>(y01, out_proj_w, x, out);
}